// Round 5
// baseline (702.354 us; speedup 1.0000x reference)
//
#include <hip/hip_runtime.h>
#include <hip/hip_bf16.h>

typedef __hip_bfloat16 bf16;
typedef __attribute__((ext_vector_type(8))) __bf16 bf16x8;
typedef __attribute__((ext_vector_type(4))) float f32x4;

#define BM 128
#define BN 128

typedef const __attribute__((address_space(1))) void gvoid;
typedef __attribute__((address_space(3))) void lvoid;

// NT GEMM: C[m,n] = sum_k A[m,k] * B[n,k]   (both row-major, K contiguous)
// MODE 0: C bf16 = acc + bias[zh*sBiasZ + m]                 (v proj)
// MODE 1: C bf16 = acc + bias[n]                             (qk proj)
// MODE 3: C bf16 = gamma[zh]*acc + xt[zb*1M + m*ldxt + n]    (o -> heads_t)
// MODE 4: C bf16 = relu(acc + bias[n])                       (fc1)
// MODE 5: out f32 scatter + residual (m local row; Cv/xf pre-offset per pass)
//
// LAYOUT 0: ntile = blockIdx.x, slice z = blockIdx.z (zb=z>>3, zh=z&7)
// LAYOUT 2: zh = blockIdx.x&7 (XCD pin), ntile = blockIdx.x>>3, zb = blockIdx.z
//   R5: LAYOUT 2 keeps one (zb,zh) slice resident per XCD -> A/B panels fit 4MB L2
//   (old slice-in-x order spanned 16MB/XCD -> L2 thrash -> LLC/HBM latency at the
//    per-K-step barrier drain; PV FETCH 210MB vs 128MB unique)
template<int MODE, int TBK, int LAYOUT>
__global__ __launch_bounds__(256)
void gemm_nt(const bf16* __restrict__ A, long lda, long sAb, long sAh,
             const bf16* __restrict__ B, long ldb, long sBb, long sBh,
             void* __restrict__ Cv, long ldc, long sCb, long sCh,
             int K,
             const float* __restrict__ bias, long sBiasZ,
             const float* __restrict__ gamma,
             const bf16* __restrict__ xt, long ldxt,
             const float* __restrict__ xf)
{
    __shared__ bf16 As[BM * TBK];
    __shared__ bf16 Bs[BN * TBK];
    const int bxt = (LAYOUT == 2) ? (blockIdx.x >> 3) : blockIdx.x;    // n-tile
    const int zb  = (LAYOUT == 2) ? blockIdx.z : (blockIdx.z >> 3);
    const int zh  = (LAYOUT == 2) ? (blockIdx.x & 7) : (blockIdx.z & 7);
    const bf16* Ab = A + (long)zb * sAb + (long)zh * sAh + (long)blockIdx.y * BM * lda;
    const bf16* Bb = B + (long)zb * sBb + (long)zh * sBh + (long)bxt * BN * ldb;
    const int tid  = threadIdx.x;
    const int wave = tid >> 6, lane = tid & 63;
    const int col  = lane & 15, quad = lane >> 4;
    const int wm = (wave & 1) * 64, wn = (wave >> 1) * 64;
    constexpr int CPR = TBK / 8;            // 16B chunks per row
    constexpr int NSLOT = TBK / 16;         // staging slots per operand
    constexpr int NX = TBK / 32;            // kk iterations

    // --- hoisted per-lane staging addresses (K-invariant shape, +TBK/step) ---
    const bf16* aAddr[NSLOT];
    const bf16* bAddr[NSLOT];
    #pragma unroll
    for (int i = 0; i < NSLOT; ++i) {
        int cbase = i * 256 + wave * 64;     // wave-uniform chunk base
        int c = cbase + lane;                // chunk id
        int m = c / CPR;                     // tile row
        int j = c % CPR;                     // chunk slot in row
        int kch = ((j ^ (m & 7)) << 3);      // swizzled k offset (elements)
        aAddr[i] = Ab + (long)m * lda + kch;
        bAddr[i] = Bb + (long)m * ldb + kch;
    }

    // --- hoisted LDS fragment byte-offsets (fully K-invariant) ---
    int offA[NX][4], offB[NX][4];
    #pragma unroll
    for (int x = 0; x < NX; ++x) {
        int kq = x * 4 + quad;               // (kk>>3)+quad with kk = x*32
        #pragma unroll
        for (int mi = 0; mi < 4; ++mi) {
            int m = wm + mi * 16 + col;
            offA[x][mi] = m * TBK + ((kq ^ (m & 7)) << 3);
            int n = wn + mi * 16 + col;
            offB[x][mi] = n * TBK + ((kq ^ (n & 7)) << 3);
        }
    }

    f32x4 acc[4][4] = {};

    for (int k0 = 0; k0 < K; k0 += TBK) {
        __syncthreads();
        #pragma unroll
        for (int i = 0; i < NSLOT; ++i) {
            int cbase = i * 256 + wave * 64;
            __builtin_amdgcn_global_load_lds(
                (gvoid*)aAddr[i], (lvoid*)(As + cbase * 8), 16, 0, 0);
            __builtin_amdgcn_global_load_lds(
                (gvoid*)bAddr[i], (lvoid*)(Bs + cbase * 8), 16, 0, 0);
            aAddr[i] += TBK;
            bAddr[i] += TBK;
        }
        __syncthreads();
        #pragma unroll
        for (int x = 0; x < NX; ++x) {
            bf16x8 af[4], bfr[4];
            #pragma unroll
            for (int mi = 0; mi < 4; ++mi)
                af[mi] = *(const bf16x8*)(As + offA[x][mi]);
            #pragma unroll
            for (int ni = 0; ni < 4; ++ni)
                bfr[ni] = *(const bf16x8*)(Bs + offB[x][ni]);
            #pragma unroll
            for (int mi = 0; mi < 4; ++mi)
                #pragma unroll
                for (int ni = 0; ni < 4; ++ni)
                    acc[mi][ni] = __builtin_amdgcn_mfma_f32_16x16x32_bf16(
                        af[mi], bfr[ni], acc[mi][ni], 0, 0, 0);
        }
    }

    const long m0 = (long)blockIdx.y * BM + wm;
    const long n0 = (long)bxt * BN + wn;
    float g = 0.f;
    if (MODE == 3) g = gamma[zh];

    // bias[n] is per-ni constant for MODE 1/4/5: preload
    float bn[4];
    if constexpr (MODE == 1 || MODE == 4 || MODE == 5) {
        #pragma unroll
        for (int ni = 0; ni < 4; ++ni)
            bn[ni] = bias[n0 + ni * 16 + col];
    }

    #pragma unroll
    for (int mi = 0; mi < 4; ++mi) {
        #pragma unroll
        for (int ni = 0; ni < 4; ++ni) {
            long mb = m0 + mi * 16 + quad * 4;
            long n  = n0 + ni * 16 + col;
            if constexpr (MODE == 0) {
                bf16* cp = (bf16*)Cv + (long)zb * sCb + (long)zh * sCh + mb * ldc + n;
                const float* bp = bias + zh * sBiasZ + mb;
                #pragma unroll
                for (int r = 0; r < 4; ++r) {
                    float v = acc[mi][ni][r] + bp[r];
                    *cp = __float2bfloat16(v);
                    cp += ldc;
                }
            } else if constexpr (MODE == 1) {
                bf16* cp = (bf16*)Cv + mb * ldc + n;
                #pragma unroll
                for (int r = 0; r < 4; ++r) {
                    float v = acc[mi][ni][r] + bn[ni];
                    *cp = __float2bfloat16(v);
                    cp += ldc;
                }
            } else if constexpr (MODE == 3) {
                bf16* cp = (bf16*)Cv + (long)zb * sCb + (long)zh * sCh + mb * ldc + n;
                const bf16* xp = xt + (long)zb * 1048576 + mb * ldxt + n;
                #pragma unroll
                for (int r = 0; r < 4; ++r) {
                    float xv = __bfloat162float(*xp);
                    *cp = __float2bfloat16(g * acc[mi][ni][r] + xv);
                    cp += ldc;
                    xp += ldxt;
                }
            } else if constexpr (MODE == 4) {
                bf16* cp = (bf16*)Cv + mb * ldc + n;
                #pragma unroll
                for (int r = 0; r < 4; ++r) {
                    float v = acc[mi][ni][r] + bn[ni];
                    v = v > 0.f ? v : 0.f;
                    *cp = __float2bfloat16(v);
                    cp += ldc;
                }
            } else {  // MODE 5: m local = bb*8192 + h*1024 + t (bb within pass)
                #pragma unroll
                for (int r = 0; r < 4; ++r) {
                    long m = mb + r;
                    float v = acc[mi][ni][r] + bn[ni];
                    v = v > 0.f ? v : 0.f;
                    long bb = m >> 13, h = (m >> 10) & 7, t = m & 1023;
                    long oi = bb * 1048576 + (n * 8 + h) * 1024 + t;
                    ((float*)Cv)[oi] = v + xf[oi];
                }
            }
        }
    }
}

// Fused energy + softmax. Grid: (slices, T/32). Block 256 (4 waves).
__global__ __launch_bounds__(256, 2)
void attn_fused(const bf16* __restrict__ qk, bf16* __restrict__ attn)
{
    constexpr int PAD = 1032;
    __shared__ __align__(16) char smraw[40960];   // phase A: Q 8K + K 32K; phase B: Sbuf 33024B
    __shared__ float red[2][4][32];
    bf16* Qs = (bf16*)smraw;                  // [32][128]
    bf16* Ks = (bf16*)(smraw + 8192);         // [128][128]
    bf16* Sbuf = (bf16*)smraw;                // [16][PAD]

    const int z = blockIdx.x;
    const int zb = z >> 3, zh = z & 7;
    const int t0 = blockIdx.y * 32;
    const int tid = threadIdx.x, w = tid >> 6, lane = tid & 63;
    const int col = lane & 15, quad = lane >> 4;

    const bf16* Qbase = qk + ((long)zb * 1024 + t0) * 2048 + zh * 256;
    const bf16* Kbase = qk + (long)zb * 1024 * 2048 + zh * 256 + 128;

    #pragma unroll
    for (int i = 0; i < 2; ++i) {
        int cbase = i * 256 + w * 64;
        int c = cbase + lane;
        int m = c >> 4, j = c & 15;
        __builtin_amdgcn_global_load_lds(
            (gvoid*)(Qbase + (long)m * 2048 + ((j ^ (m & 7)) << 3)),
            (lvoid*)(Qs + cbase * 8), 16, 0, 0);
    }
    __syncthreads();
    bf16x8 af[2][4];
    #pragma unroll
    for (int mi = 0; mi < 2; ++mi) {
        int m = mi * 16 + col;
        #pragma unroll
        for (int ki = 0; ki < 4; ++ki)
            af[mi][ki] = *(const bf16x8*)(Qs + m * 128 + ((((ki << 2) + quad) ^ (m & 7)) << 3));
    }

    f32x4 acc[2][16] = {};
    #pragma unroll
    for (int si = 0; si < 8; ++si) {
        __syncthreads();
        const bf16* Kb = Kbase + (long)si * 128 * 2048;
        #pragma unroll
        for (int i = 0; i < 8; ++i) {
            int cbase = i * 256 + w * 64;
            int c = cbase + lane;
            int m = c >> 4, j = c & 15;
            __builtin_amdgcn_global_load_lds(
                (gvoid*)(Kb + (long)m * 2048 + ((j ^ (m & 7)) << 3)),
                (lvoid*)(Ks + cbase * 8), 16, 0, 0);
        }
        __syncthreads();
        bf16x8 bfr[2][4];
        #pragma unroll
        for (int ni = 0; ni < 2; ++ni) {
            int n = w * 32 + ni * 16 + col;
            #pragma unroll
            for (int ki = 0; ki < 4; ++ki)
                bfr[ni][ki] = *(const bf16x8*)(Ks + n * 128 + ((((ki << 2) + quad) ^ (n & 7)) << 3));
        }
        #pragma unroll
        for (int ki = 0; ki < 4; ++ki)
            #pragma unroll
            for (int mi = 0; mi < 2; ++mi)
                #pragma unroll
                for (int ni = 0; ni < 2; ++ni)
                    acc[mi][si * 2 + ni] = __builtin_amdgcn_mfma_f32_16x16x32_bf16(
                        af[mi][ki], bfr[ni][ki], acc[mi][si * 2 + ni], 0, 0, 0);
    }

    float rmx[2][4], rinv[2][4];
    #pragma unroll
    for (int mi = 0; mi < 2; ++mi)
        #pragma unroll
        for (int r = 0; r < 4; ++r) {
            float mx = acc[mi][0][r];
            #pragma unroll
            for (int j = 1; j < 16; ++j) mx = fmaxf(mx, acc[mi][j][r]);
            #pragma unroll
            for (int off = 1; off < 16; off <<= 1) mx = fmaxf(mx, __shfl_xor(mx, off, 64));
            rmx[mi][r] = mx;
        }
    if (col == 0) {
        #pragma unroll
        for (int mi = 0; mi < 2; ++mi)
            #pragma unroll
            for (int r = 0; r < 4; ++r)
                red[0][w][mi * 16 + quad * 4 + r] = rmx[mi][r];
    }
    __syncthreads();
    #pragma unroll
    for (int mi = 0; mi < 2; ++mi)
        #pragma unroll
        for (int r = 0; r < 4; ++r) {
            int row = mi * 16 + quad * 4 + r;
            rmx[mi][r] = fmaxf(fmaxf(red[0][0][row], red[0][1][row]),
                               fmaxf(red[0][2][row], red[0][3][row]));
        }
    #pragma unroll
    for (int mi = 0; mi < 2; ++mi)
        #pragma unroll
        for (int r = 0; r < 4; ++r) {
            float s = 0.f;
            #pragma unroll
            for (int j = 0; j < 16; ++j) {
                acc[mi][j][r] = __expf(acc[mi][j][r] - rmx[mi][r]);
                s += acc[mi][j][r];
            }
            #pragma unroll
            for (int off = 1; off < 16; off <<= 1) s += __shfl_xor(s, off, 64);
            rinv[mi][r] = s;
        }
    if (col == 0) {
        #pragma unroll
        for (int mi = 0; mi < 2; ++mi)
            #pragma unroll
            for (int r = 0; r < 4; ++r)
                red[1][w][mi * 16 + quad * 4 + r] = rinv[mi][r];
    }
    __syncthreads();
    #pragma unroll
    for (int mi = 0; mi < 2; ++mi)
        #pragma unroll
        for (int r = 0; r < 4; ++r) {
            int row = mi * 16 + quad * 4 + r;
            float s4 = red[1][0][row] + red[1][1][row] + red[1][2][row] + red[1][3][row];
            rinv[mi][r] = 1.0f / s4;
        }

    bf16* dst = attn + ((long)(zb * 8 + zh)) * 1048576 + (long)t0 * 1024;
    #pragma unroll
    for (int mi = 0; mi < 2; ++mi) {
        __syncthreads();
        #pragma unroll
        for (int j = 0; j < 16; ++j) {
            int colb = (j >> 1) * 128 + w * 32 + (j & 1) * 16 + col;
            #pragma unroll
            for (int r = 0; r < 4; ++r) {
                int rowh = quad * 4 + r;
                Sbuf[rowh * PAD + colb] = __float2bfloat16(acc[mi][j][r] * rinv[mi][r]);
            }
        }
        __syncthreads();
        #pragma unroll
        for (int i = 0; i < 8; ++i) {
            int c = i * 256 + tid;             // 16 rows x 128 chunks
            int rowh = c >> 7, jj = c & 127;
            bf16x8 vv = *(const bf16x8*)(Sbuf + rowh * PAD + jj * 8);
            *(bf16x8*)(dst + (long)(mi * 16 + rowh) * 1024 + jj * 8) = vv;
        }
    }
}

// x (B,C,T) f32 -> xt (B,T,C) bf16, 32x32 LDS tiles
__global__ __launch_bounds__(256)
void transpose_cast_x(const float* __restrict__ x, bf16* __restrict__ xt)
{
    __shared__ float tile[32][33];
    int b = blockIdx.z;
    int c0 = blockIdx.y * 32, t0 = blockIdx.x * 32;
    int tx = threadIdx.x & 31, ty = threadIdx.x >> 5;  // ty 0..7
    const float* xb = x + (long)b * 1024 * 1024;
    #pragma unroll
    for (int i = 0; i < 4; ++i) {
        int c = ty + i * 8;
        tile[c][tx] = xb[(long)(c0 + c) * 1024 + t0 + tx];
    }
    __syncthreads();
    bf16* xtb = xt + (long)b * 1024 * 1024;
    #pragma unroll
    for (int i = 0; i < 4; ++i) {
        int t = ty + i * 8;
        xtb[(long)(t0 + t) * 1024 + c0 + tx] = __float2bfloat16(tile[tx][t]);
    }
}

__global__ __launch_bounds__(256)
void cast_f2b(const float* __restrict__ in, bf16* __restrict__ out, long n)
{
    long i = (long)blockIdx.x * 256 + threadIdx.x;
    long stride = (long)gridDim.x * 256;
    for (; i < n; i += stride) out[i] = __float2bfloat16(in[i]);
}

// Build stacked qk weight (2048 x 1024 bf16)
__global__ __launch_bounds__(256)
void build_wqk(const float* __restrict__ Wq, const float* __restrict__ Wk,
               const float* __restrict__ bq, const float* __restrict__ bk,
               bf16* __restrict__ Wqk, float* __restrict__ biasqk)
{
    long i = (long)blockIdx.x * 256 + threadIdx.x;   // 2048*1024 total
    long r = i >> 10, c = i & 1023;
    long h = r >> 8, rr = r & 255;
    float v = (rr < 128) ? Wq[(h * 128 + rr) * 1024 + c]
                         : Wk[(h * 128 + (rr - 128)) * 1024 + c];
    Wqk[i] = __float2bfloat16(v);
    if (c == 0)
        biasqk[r] = (rr < 128) ? bq[h * 128 + rr] : bk[h * 128 + rr - 128];
}

extern "C" void kernel_launch(void* const* d_in, const int* in_sizes, int n_in,
                              void* d_out, int out_size, void* d_ws, size_t ws_size,
                              hipStream_t stream)
{
    const float* x     = (const float*)d_in[0];
    const float* Wq    = (const float*)d_in[1];
    const float* bq    = (const float*)d_in[2];
    const float* Wk    = (const float*)d_in[3];
    const float* bk    = (const float*)d_in[4];
    const float* Wv    = (const float*)d_in[5];
    const float* bv    = (const float*)d_in[6];
    const float* gamma = (const float*)d_in[7];
    const float* W1    = (const float*)d_in[8];
    const float* b1    = (const float*)d_in[9];
    const float* W2    = (const float*)d_in[10];
    const float* b2    = (const float*)d_in[11];
    float* out = (float*)d_out;

    // chunk=4, two passes. Workspace (256 MiB exactly), MiB offsets:
    // [0,16)    xt            (live whole run)
    // [16,32)   Wvb           (live through pass-2 v-proj)
    // [32,96)   vbuf (pass)   — Wqk@[32,36) + bqk@[36,..) overlay, dead before pass-1 v
    // [96,160)  attb (pass)   — post-O per pass: W1b@96, W2b@96+0.5M, y1c@[97,105)
    // [160,224) ot   (pass)
    // [224,256) qkt           (live through pass-2 attn_fused)
    char* base = (char*)d_ws;
    const long MB = 1048576;
    bf16*  xt   = (bf16*)(base);
    bf16*  Wvb  = (bf16*)(base + 16 * MB);
    bf16*  vbuf = (bf16*)(base + 32 * MB);
    bf16*  Wqk  = (bf16*)(base + 32 * MB);          // dead after qk-proj
    float* bqk  = (float*)(base + 36 * MB);         // dead after qk-proj
    bf16*  attb = (bf16*)(base + 96 * MB);
    bf16*  W1b  = (bf16*)(base + 96 * MB);          // post-O overlay, re-cast per pass
    bf16*  W2b  = (bf16*)(base + 96 * MB + 524288);
    bf16*  y1c  = (bf16*)(base + 97 * MB);          // 8 MiB per pass
    bf16*  ot   = (bf16*)(base + 160 * MB);
    bf16*  qkt  = (bf16*)(base + 224 * MB);

    dim3 blk(256);
    transpose_cast_x<<<dim3(32, 32, 8), blk, 0, stream>>>(x, xt);
    build_wqk<<<8192, blk, 0, stream>>>(Wq, Wk, bq, bk, Wqk, bqk);
    cast_f2b<<<4096, blk, 0, stream>>>(Wv, Wvb, 8192ll * 1024);

    const long M1 = 1048576, M2 = 2097152, M8 = 8388608;

    // qk_t: M=8192 (b,t), N=2048 (h*256+o), K=1024 — full batch
    gemm_nt<1, 64, 0><<<dim3(16, 64, 1), blk, 0, stream>>>(
        xt, 1024, 0, 0, Wqk, 1024, 0, 0, qkt, 2048, 0, 0, 1024,
        bqk, 0, nullptr, nullptr, 0, nullptr);

    for (int q = 0; q < 2; ++q) {
        const long b0 = (long)q * 4;
        const bf16* xtq = xt + b0 * M1;
        // v(zb,zh;c,s) = Wv[zh](c,ci) . xt(b0+zb;s,ci)^T + bv[zh,c]
        // LAYOUT 2: x = zh + 8*ntile (XCD-pinned head), z = zb slowest ->
        // per-XCD working set = Wv[zh] 2MB + xt[zb] 2MB ~= L2
        gemm_nt<0, 64, 2><<<dim3(64, 8, 4), blk, 0, stream>>>(
            Wvb, 1024, 0, M1, xtq, 1024, M1, 0, vbuf, 1024, M8, M1, 1024,
            bv, 1024, nullptr, nullptr, 0, nullptr);
        // fused E + softmax -> attb bf16 (1024 blocks)
        attn_fused<<<dim3(32, 32, 1), blk, 0, stream>>>(
            qkt + b0 * M2, attb);
        // heads_t(zb,zh;t,c) = gamma[zh]*(attn(t,s).v(c,s)^T) + xt(b0+zb;t,c)
        // LAYOUT 2: per-XCD working set = attb[zb,zh] 2MB + vbuf[zb,zh] 2MB ~= L2
        gemm_nt<3, 64, 2><<<dim3(64, 8, 4), blk, 0, stream>>>(
            attb, 1024, M8, M1, vbuf, 1024, M8, M1,
            ot, 1024, M8, M1, 1024,
            nullptr, 0, gamma, xtq, 1024, nullptr);
        // attb dead: cast FC weights into its region (re-done each pass)
        cast_f2b<<<512, blk, 0, stream>>>(W1, W1b, 128 * 1024);
        cast_f2b<<<64, blk, 0, stream>>>(W2, W2b, 128 * 128);
        // y1c = relu(ot . W1^T + b1): M=32768, N=128, K=1024 (256 blocks, ot LLC-warm)
        gemm_nt<4, 64, 0><<<dim3(1, 256, 1), blk, 0, stream>>>(
            ot, 1024, 0, 0, W1b, 1024, 0, 0, y1c, 128, 0, 0, 1024,
            b1, 0, nullptr, nullptr, 0, nullptr);
        // out = relu(y1c . W2^T + b2) scattered + x (pass-local rows)
        gemm_nt<5, 128, 0><<<dim3(1, 256, 1), blk, 0, stream>>>(
            y1c, 128, 0, 0, W2b, 128, 0, 0, out + b0 * M1, 0, 0, 0, 128,
            b2, 0, nullptr, nullptr, 0, x + b0 * M1);
    }
}

// Round 6
// 676.691 us; speedup vs baseline: 1.0379x; 1.0379x over previous
//
#include <hip/hip_runtime.h>
#include <hip/hip_bf16.h>

typedef __hip_bfloat16 bf16;
typedef __attribute__((ext_vector_type(8))) __bf16 bf16x8;
typedef __attribute__((ext_vector_type(4))) float f32x4;

#define BM 128
#define BN 128

typedef const __attribute__((address_space(1))) void gvoid;
typedef __attribute__((address_space(3))) void lvoid;

// ---------------------------------------------------------------------------
// gemm256: counted-vmcnt ring-pipelined NT GEMM for the two 137-GFLOP passes.
// C[m,n] = sum_k A[m,k]*B[n,k]. Tile 256x128, BK=64, 512 thr (8 waves, 4Mx2N).
// LDS ring: 3 slots x (A 256x64 + B 128x64) bf16 = 144 KB -> 1 block/CU.
// Pipeline: compute K-tile t from slot t%3 while tile t+2's global_load_lds
// fly; vmcnt(6) at iter end drains only tile t+1 (6 loads/thread/tile),
// keeping t+2 in flight ACROSS the barrier (T3+T4). Uniform branches only.
// MODE 0: C = acc + bias[zh*sBiasZ+m] (v-proj); MODE 3: gamma*acc + xt (PV).
// ---------------------------------------------------------------------------
template<int MODE>
__global__ __launch_bounds__(512)
void gemm256(const bf16* __restrict__ A, long lda, long sAb, long sAh,
             const bf16* __restrict__ B, long ldb, long sBb, long sBh,
             void* __restrict__ Cv, long ldc, long sCb, long sCh,
             int K,
             const float* __restrict__ bias, long sBiasZ,
             const float* __restrict__ gamma,
             const bf16* __restrict__ xt, long ldxt)
{
    __shared__ bf16 ring[3][(256 + 128) * 64];   // 147456 B
    const int nt4 = blockIdx.x >> 3;             // n-tile (0..7)
    const int zh  = blockIdx.x & 7;              // XCD-pinned head
    const int zb  = blockIdx.z;
    const bf16* Ab = A + (long)zb * sAb + (long)zh * sAh + (long)blockIdx.y * 256 * lda;
    const bf16* Bb = B + (long)zb * sBb + (long)zh * sBh + (long)nt4 * 128 * ldb;
    const int tid = threadIdx.x;
    const int wave = tid >> 6, lane = tid & 63;
    const int col = lane & 15, quad = lane >> 4;
    const int wm = (wave >> 1) * 64, wn = (wave & 1) * 64;

    // staging: A 2048 chunks (4/thread), B 1024 chunks (2/thread); 16B each
    const bf16* aAddr[4];
    const bf16* bAddr[2];
    int aDst[4], bDst[2];
    #pragma unroll
    for (int i = 0; i < 4; ++i) {
        int cbase = i * 512 + wave * 64;         // wave-uniform chunk base
        int c = cbase + lane;
        int m = c >> 3, j = c & 7;
        aAddr[i] = Ab + (long)m * lda + ((j ^ (m & 7)) << 3);
        aDst[i] = cbase * 8;
    }
    #pragma unroll
    for (int i = 0; i < 2; ++i) {
        int cbase = i * 512 + wave * 64;
        int c = cbase + lane;
        int m = c >> 3, j = c & 7;
        bAddr[i] = Bb + (long)m * ldb + ((j ^ (m & 7)) << 3);
        bDst[i] = 16384 + cbase * 8;             // B region after A (256*64)
    }

    // K-invariant LDS fragment element-offsets (within a slot)
    int offA[2][4], offB[2][4];
    #pragma unroll
    for (int x = 0; x < 2; ++x) {
        int kq = x * 4 + quad;
        #pragma unroll
        for (int mi = 0; mi < 4; ++mi) {
            int m = wm + mi * 16 + col;
            offA[x][mi] = m * 64 + ((kq ^ (m & 7)) << 3);
            int n = wn + mi * 16 + col;
            offB[x][mi] = 16384 + n * 64 + ((kq ^ (n & 7)) << 3);
        }
    }

    f32x4 acc[4][4] = {};

    auto STAGE = [&](int rb) {
        bf16* base = &ring[rb][0];
        #pragma unroll
        for (int i = 0; i < 4; ++i) {
            __builtin_amdgcn_global_load_lds((gvoid*)aAddr[i], (lvoid*)(base + aDst[i]), 16, 0, 0);
            aAddr[i] += 64;
        }
        #pragma unroll
        for (int i = 0; i < 2; ++i) {
            __builtin_amdgcn_global_load_lds((gvoid*)bAddr[i], (lvoid*)(base + bDst[i]), 16, 0, 0);
            bAddr[i] += 64;
        }
    };

    const int NT = K >> 6;                        // 16 K-tiles
    STAGE(0);
    STAGE(1);                                     // 12 loads in flight
    asm volatile("s_waitcnt vmcnt(6)" ::: "memory");  // tile0 landed, tile1 flying
    __builtin_amdgcn_s_barrier();
    __builtin_amdgcn_sched_barrier(0);

    int rc = 0;
    for (int t = 0; t < NT; ++t) {
        int r2 = rc + 2; if (r2 >= 3) r2 -= 3;
        if (t + 2 < NT) STAGE(r2);                // issue tile t+2 early
        const bf16* buf = &ring[rc][0];
        #pragma unroll
        for (int x = 0; x < 2; ++x) {
            bf16x8 af[4], bfr[4];
            #pragma unroll
            for (int mi = 0; mi < 4; ++mi)
                af[mi] = *(const bf16x8*)(buf + offA[x][mi]);
            #pragma unroll
            for (int ni = 0; ni < 4; ++ni)
                bfr[ni] = *(const bf16x8*)(buf + offB[x][ni]);
            #pragma unroll
            for (int mi = 0; mi < 4; ++mi)
                #pragma unroll
                for (int ni = 0; ni < 4; ++ni)
                    acc[mi][ni] = __builtin_amdgcn_mfma_f32_16x16x32_bf16(
                        af[mi], bfr[ni], acc[mi][ni], 0, 0, 0);
        }
        if (t + 2 < NT)
            asm volatile("s_waitcnt vmcnt(6)" ::: "memory");   // t+1 landed, t+2 flying
        else if (t + 1 < NT)
            asm volatile("s_waitcnt vmcnt(0)" ::: "memory");   // drain last stage
        if (t + 1 < NT) {
            __builtin_amdgcn_s_barrier();
            __builtin_amdgcn_sched_barrier(0);
        }
        rc = rc + 1; if (rc >= 3) rc -= 3;
    }

    const long m0 = (long)blockIdx.y * 256 + wm;
    const long n0 = (long)nt4 * 128 + wn;
    float g = 0.f;
    if (MODE == 3) g = gamma[zh];
    #pragma unroll
    for (int mi = 0; mi < 4; ++mi) {
        #pragma unroll
        for (int ni = 0; ni < 4; ++ni) {
            long mb = m0 + mi * 16 + quad * 4;
            long n  = n0 + ni * 16 + col;
            if constexpr (MODE == 0) {
                bf16* cp = (bf16*)Cv + (long)zb * sCb + (long)zh * sCh + mb * ldc + n;
                const float* bp = bias + zh * sBiasZ + mb;
                #pragma unroll
                for (int r = 0; r < 4; ++r) {
                    *cp = __float2bfloat16(acc[mi][ni][r] + bp[r]);
                    cp += ldc;
                }
            } else {
                bf16* cp = (bf16*)Cv + (long)zb * sCb + (long)zh * sCh + mb * ldc + n;
                const bf16* xp = xt + (long)zb * 1048576 + mb * ldxt + n;
                #pragma unroll
                for (int r = 0; r < 4; ++r) {
                    float xv = __bfloat162float(*xp);
                    *cp = __float2bfloat16(g * acc[mi][ni][r] + xv);
                    cp += ldc;
                    xp += ldxt;
                }
            }
        }
    }
}

// NT GEMM: C[m,n] = sum_k A[m,k] * B[n,k]   (both row-major, K contiguous)
// MODE 1: C bf16 = acc + bias[n]                             (qk proj)
// MODE 4: C bf16 = relu(acc + bias[n])                       (fc1)
// MODE 5: out f32 scatter + residual (m local row; Cv/xf pre-offset per pass)
template<int MODE, int TBK, int LAYOUT>
__global__ __launch_bounds__(256)
void gemm_nt(const bf16* __restrict__ A, long lda, long sAb, long sAh,
             const bf16* __restrict__ B, long ldb, long sBb, long sBh,
             void* __restrict__ Cv, long ldc, long sCb, long sCh,
             int K,
             const float* __restrict__ bias, long sBiasZ,
             const float* __restrict__ gamma,
             const bf16* __restrict__ xt, long ldxt,
             const float* __restrict__ xf)
{
    __shared__ bf16 As[BM * TBK];
    __shared__ bf16 Bs[BN * TBK];
    const int bxt = (LAYOUT == 2) ? (blockIdx.x >> 3) : blockIdx.x;    // n-tile
    const int zb  = (LAYOUT == 2) ? blockIdx.z : (blockIdx.z >> 3);
    const int zh  = (LAYOUT == 2) ? (blockIdx.x & 7) : (blockIdx.z & 7);
    const bf16* Ab = A + (long)zb * sAb + (long)zh * sAh + (long)blockIdx.y * BM * lda;
    const bf16* Bb = B + (long)zb * sBb + (long)zh * sBh + (long)bxt * BN * ldb;
    const int tid  = threadIdx.x;
    const int wave = tid >> 6, lane = tid & 63;
    const int col  = lane & 15, quad = lane >> 4;
    const int wm = (wave & 1) * 64, wn = (wave >> 1) * 64;
    constexpr int CPR = TBK / 8;            // 16B chunks per row
    constexpr int NSLOT = TBK / 16;         // staging slots per operand
    constexpr int NX = TBK / 32;            // kk iterations

    const bf16* aAddr[NSLOT];
    const bf16* bAddr[NSLOT];
    #pragma unroll
    for (int i = 0; i < NSLOT; ++i) {
        int cbase = i * 256 + wave * 64;     // wave-uniform chunk base
        int c = cbase + lane;                // chunk id
        int m = c / CPR;                     // tile row
        int j = c % CPR;                     // chunk slot in row
        int kch = ((j ^ (m & 7)) << 3);      // swizzled k offset (elements)
        aAddr[i] = Ab + (long)m * lda + kch;
        bAddr[i] = Bb + (long)m * ldb + kch;
    }

    int offA[NX][4], offB[NX][4];
    #pragma unroll
    for (int x = 0; x < NX; ++x) {
        int kq = x * 4 + quad;               // (kk>>3)+quad with kk = x*32
        #pragma unroll
        for (int mi = 0; mi < 4; ++mi) {
            int m = wm + mi * 16 + col;
            offA[x][mi] = m * TBK + ((kq ^ (m & 7)) << 3);
            int n = wn + mi * 16 + col;
            offB[x][mi] = n * TBK + ((kq ^ (n & 7)) << 3);
        }
    }

    f32x4 acc[4][4] = {};

    for (int k0 = 0; k0 < K; k0 += TBK) {
        __syncthreads();
        #pragma unroll
        for (int i = 0; i < NSLOT; ++i) {
            int cbase = i * 256 + wave * 64;
            __builtin_amdgcn_global_load_lds(
                (gvoid*)aAddr[i], (lvoid*)(As + cbase * 8), 16, 0, 0);
            __builtin_amdgcn_global_load_lds(
                (gvoid*)bAddr[i], (lvoid*)(Bs + cbase * 8), 16, 0, 0);
            aAddr[i] += TBK;
            bAddr[i] += TBK;
        }
        __syncthreads();
        #pragma unroll
        for (int x = 0; x < NX; ++x) {
            bf16x8 af[4], bfr[4];
            #pragma unroll
            for (int mi = 0; mi < 4; ++mi)
                af[mi] = *(const bf16x8*)(As + offA[x][mi]);
            #pragma unroll
            for (int ni = 0; ni < 4; ++ni)
                bfr[ni] = *(const bf16x8*)(Bs + offB[x][ni]);
            #pragma unroll
            for (int mi = 0; mi < 4; ++mi)
                #pragma unroll
                for (int ni = 0; ni < 4; ++ni)
                    acc[mi][ni] = __builtin_amdgcn_mfma_f32_16x16x32_bf16(
                        af[mi], bfr[ni], acc[mi][ni], 0, 0, 0);
        }
    }

    const long m0 = (long)blockIdx.y * BM + wm;
    const long n0 = (long)bxt * BN + wn;
    float g = 0.f;
    if (MODE == 3) g = gamma[zh];

    float bn[4];
    if constexpr (MODE == 1 || MODE == 4 || MODE == 5) {
        #pragma unroll
        for (int ni = 0; ni < 4; ++ni)
            bn[ni] = bias[n0 + ni * 16 + col];
    }

    #pragma unroll
    for (int mi = 0; mi < 4; ++mi) {
        #pragma unroll
        for (int ni = 0; ni < 4; ++ni) {
            long mb = m0 + mi * 16 + quad * 4;
            long n  = n0 + ni * 16 + col;
            if constexpr (MODE == 0) {
                bf16* cp = (bf16*)Cv + (long)zb * sCb + (long)zh * sCh + mb * ldc + n;
                const float* bp = bias + zh * sBiasZ + mb;
                #pragma unroll
                for (int r = 0; r < 4; ++r) {
                    float v = acc[mi][ni][r] + bp[r];
                    *cp = __float2bfloat16(v);
                    cp += ldc;
                }
            } else if constexpr (MODE == 1) {
                bf16* cp = (bf16*)Cv + mb * ldc + n;
                #pragma unroll
                for (int r = 0; r < 4; ++r) {
                    float v = acc[mi][ni][r] + bn[ni];
                    *cp = __float2bfloat16(v);
                    cp += ldc;
                }
            } else if constexpr (MODE == 3) {
                bf16* cp = (bf16*)Cv + (long)zb * sCb + (long)zh * sCh + mb * ldc + n;
                const bf16* xp = xt + (long)zb * 1048576 + mb * ldxt + n;
                #pragma unroll
                for (int r = 0; r < 4; ++r) {
                    float xv = __bfloat162float(*xp);
                    *cp = __float2bfloat16(g * acc[mi][ni][r] + xv);
                    cp += ldc;
                    xp += ldxt;
                }
            } else if constexpr (MODE == 4) {
                bf16* cp = (bf16*)Cv + mb * ldc + n;
                #pragma unroll
                for (int r = 0; r < 4; ++r) {
                    float v = acc[mi][ni][r] + bn[ni];
                    v = v > 0.f ? v : 0.f;
                    *cp = __float2bfloat16(v);
                    cp += ldc;
                }
            } else {  // MODE 5
                #pragma unroll
                for (int r = 0; r < 4; ++r) {
                    long m = mb + r;
                    float v = acc[mi][ni][r] + bn[ni];
                    v = v > 0.f ? v : 0.f;
                    long bb = m >> 13, h = (m >> 10) & 7, t = m & 1023;
                    long oi = bb * 1048576 + (n * 8 + h) * 1024 + t;
                    ((float*)Cv)[oi] = v + xf[oi];
                }
            }
        }
    }
}

// Fused energy + softmax. Grid: (slices, T/32). Block 256 (4 waves).
__global__ __launch_bounds__(256, 2)
void attn_fused(const bf16* __restrict__ qk, bf16* __restrict__ attn)
{
    constexpr int PAD = 1032;
    __shared__ __align__(16) char smraw[40960];
    __shared__ float red[2][4][32];
    bf16* Qs = (bf16*)smraw;                  // [32][128]
    bf16* Ks = (bf16*)(smraw + 8192);         // [128][128]
    bf16* Sbuf = (bf16*)smraw;                // [16][PAD]

    const int z = blockIdx.x;
    const int zb = z >> 3, zh = z & 7;
    const int t0 = blockIdx.y * 32;
    const int tid = threadIdx.x, w = tid >> 6, lane = tid & 63;
    const int col = lane & 15, quad = lane >> 4;

    const bf16* Qbase = qk + ((long)zb * 1024 + t0) * 2048 + zh * 256;
    const bf16* Kbase = qk + (long)zb * 1024 * 2048 + zh * 256 + 128;

    #pragma unroll
    for (int i = 0; i < 2; ++i) {
        int cbase = i * 256 + w * 64;
        int c = cbase + lane;
        int m = c >> 4, j = c & 15;
        __builtin_amdgcn_global_load_lds(
            (gvoid*)(Qbase + (long)m * 2048 + ((j ^ (m & 7)) << 3)),
            (lvoid*)(Qs + cbase * 8), 16, 0, 0);
    }
    __syncthreads();
    bf16x8 af[2][4];
    #pragma unroll
    for (int mi = 0; mi < 2; ++mi) {
        int m = mi * 16 + col;
        #pragma unroll
        for (int ki = 0; ki < 4; ++ki)
            af[mi][ki] = *(const bf16x8*)(Qs + m * 128 + ((((ki << 2) + quad) ^ (m & 7)) << 3));
    }

    f32x4 acc[2][16] = {};
    #pragma unroll
    for (int si = 0; si < 8; ++si) {
        __syncthreads();
        const bf16* Kb = Kbase + (long)si * 128 * 2048;
        #pragma unroll
        for (int i = 0; i < 8; ++i) {
            int cbase = i * 256 + w * 64;
            int c = cbase + lane;
            int m = c >> 4, j = c & 15;
            __builtin_amdgcn_global_load_lds(
                (gvoid*)(Kb + (long)m * 2048 + ((j ^ (m & 7)) << 3)),
                (lvoid*)(Ks + cbase * 8), 16, 0, 0);
        }
        __syncthreads();
        bf16x8 bfr[2][4];
        #pragma unroll
        for (int ni = 0; ni < 2; ++ni) {
            int n = w * 32 + ni * 16 + col;
            #pragma unroll
            for (int ki = 0; ki < 4; ++ki)
                bfr[ni][ki] = *(const bf16x8*)(Ks + n * 128 + ((((ki << 2) + quad) ^ (n & 7)) << 3));
        }
        #pragma unroll
        for (int ki = 0; ki < 4; ++ki)
            #pragma unroll
            for (int mi = 0; mi < 2; ++mi)
                #pragma unroll
                for (int ni = 0; ni < 2; ++ni)
                    acc[mi][si * 2 + ni] = __builtin_amdgcn_mfma_f32_16x16x32_bf16(
                        af[mi][ki], bfr[ni][ki], acc[mi][si * 2 + ni], 0, 0, 0);
    }

    float rmx[2][4], rinv[2][4];
    #pragma unroll
    for (int mi = 0; mi < 2; ++mi)
        #pragma unroll
        for (int r = 0; r < 4; ++r) {
            float mx = acc[mi][0][r];
            #pragma unroll
            for (int j = 1; j < 16; ++j) mx = fmaxf(mx, acc[mi][j][r]);
            #pragma unroll
            for (int off = 1; off < 16; off <<= 1) mx = fmaxf(mx, __shfl_xor(mx, off, 64));
            rmx[mi][r] = mx;
        }
    if (col == 0) {
        #pragma unroll
        for (int mi = 0; mi < 2; ++mi)
            #pragma unroll
            for (int r = 0; r < 4; ++r)
                red[0][w][mi * 16 + quad * 4 + r] = rmx[mi][r];
    }
    __syncthreads();
    #pragma unroll
    for (int mi = 0; mi < 2; ++mi)
        #pragma unroll
        for (int r = 0; r < 4; ++r) {
            int row = mi * 16 + quad * 4 + r;
            rmx[mi][r] = fmaxf(fmaxf(red[0][0][row], red[0][1][row]),
                               fmaxf(red[0][2][row], red[0][3][row]));
        }
    #pragma unroll
    for (int mi = 0; mi < 2; ++mi)
        #pragma unroll
        for (int r = 0; r < 4; ++r) {
            float s = 0.f;
            #pragma unroll
            for (int j = 0; j < 16; ++j) {
                acc[mi][j][r] = __expf(acc[mi][j][r] - rmx[mi][r]);
                s += acc[mi][j][r];
            }
            #pragma unroll
            for (int off = 1; off < 16; off <<= 1) s += __shfl_xor(s, off, 64);
            rinv[mi][r] = s;
        }
    if (col == 0) {
        #pragma unroll
        for (int mi = 0; mi < 2; ++mi)
            #pragma unroll
            for (int r = 0; r < 4; ++r)
                red[1][w][mi * 16 + quad * 4 + r] = rinv[mi][r];
    }
    __syncthreads();
    #pragma unroll
    for (int mi = 0; mi < 2; ++mi)
        #pragma unroll
        for (int r = 0; r < 4; ++r) {
            int row = mi * 16 + quad * 4 + r;
            float s4 = red[1][0][row] + red[1][1][row] + red[1][2][row] + red[1][3][row];
            rinv[mi][r] = 1.0f / s4;
        }

    bf16* dst = attn + ((long)(zb * 8 + zh)) * 1048576 + (long)t0 * 1024;
    #pragma unroll
    for (int mi = 0; mi < 2; ++mi) {
        __syncthreads();
        #pragma unroll
        for (int j = 0; j < 16; ++j) {
            int colb = (j >> 1) * 128 + w * 32 + (j & 1) * 16 + col;
            #pragma unroll
            for (int r = 0; r < 4; ++r) {
                int rowh = quad * 4 + r;
                Sbuf[rowh * PAD + colb] = __float2bfloat16(acc[mi][j][r] * rinv[mi][r]);
            }
        }
        __syncthreads();
        #pragma unroll
        for (int i = 0; i < 8; ++i) {
            int c = i * 256 + tid;             // 16 rows x 128 chunks
            int rowh = c >> 7, jj = c & 127;
            bf16x8 vv = *(const bf16x8*)(Sbuf + rowh * PAD + jj * 8);
            *(bf16x8*)(dst + (long)(mi * 16 + rowh) * 1024 + jj * 8) = vv;
        }
    }
}

// x (B,C,T) f32 -> xt (B,T,C) bf16, 32x32 LDS tiles
__global__ __launch_bounds__(256)
void transpose_cast_x(const float* __restrict__ x, bf16* __restrict__ xt)
{
    __shared__ float tile[32][33];
    int b = blockIdx.z;
    int c0 = blockIdx.y * 32, t0 = blockIdx.x * 32;
    int tx = threadIdx.x & 31, ty = threadIdx.x >> 5;  // ty 0..7
    const float* xb = x + (long)b * 1024 * 1024;
    #pragma unroll
    for (int i = 0; i < 4; ++i) {
        int c = ty + i * 8;
        tile[c][tx] = xb[(long)(c0 + c) * 1024 + t0 + tx];
    }
    __syncthreads();
    bf16* xtb = xt + (long)b * 1024 * 1024;
    #pragma unroll
    for (int i = 0; i < 4; ++i) {
        int t = ty + i * 8;
        xtb[(long)(t0 + t) * 1024 + c0 + tx] = __float2bfloat16(tile[tx][t]);
    }
}

__global__ __launch_bounds__(256)
void cast_f2b(const float* __restrict__ in, bf16* __restrict__ out, long n)
{
    long i = (long)blockIdx.x * 256 + threadIdx.x;
    long stride = (long)gridDim.x * 256;
    for (; i < n; i += stride) out[i] = __float2bfloat16(in[i]);
}

// Build stacked qk weight (2048 x 1024 bf16)
__global__ __launch_bounds__(256)
void build_wqk(const float* __restrict__ Wq, const float* __restrict__ Wk,
               const float* __restrict__ bq, const float* __restrict__ bk,
               bf16* __restrict__ Wqk, float* __restrict__ biasqk)
{
    long i = (long)blockIdx.x * 256 + threadIdx.x;   // 2048*1024 total
    long r = i >> 10, c = i & 1023;
    long h = r >> 8, rr = r & 255;
    float v = (rr < 128) ? Wq[(h * 128 + rr) * 1024 + c]
                         : Wk[(h * 128 + (rr - 128)) * 1024 + c];
    Wqk[i] = __float2bfloat16(v);
    if (c == 0)
        biasqk[r] = (rr < 128) ? bq[h * 128 + rr] : bk[h * 128 + rr - 128];
}

extern "C" void kernel_launch(void* const* d_in, const int* in_sizes, int n_in,
                              void* d_out, int out_size, void* d_ws, size_t ws_size,
                              hipStream_t stream)
{
    const float* x     = (const float*)d_in[0];
    const float* Wq    = (const float*)d_in[1];
    const float* bq    = (const float*)d_in[2];
    const float* Wk    = (const float*)d_in[3];
    const float* bk    = (const float*)d_in[4];
    const float* Wv    = (const float*)d_in[5];
    const float* bv    = (const float*)d_in[6];
    const float* gamma = (const float*)d_in[7];
    const float* W1    = (const float*)d_in[8];
    const float* b1    = (const float*)d_in[9];
    const float* W2    = (const float*)d_in[10];
    const float* b2    = (const float*)d_in[11];
    float* out = (float*)d_out;

    char* base = (char*)d_ws;
    const long MB = 1048576;
    bf16*  xt   = (bf16*)(base);
    bf16*  Wvb  = (bf16*)(base + 16 * MB);
    bf16*  vbuf = (bf16*)(base + 32 * MB);
    bf16*  Wqk  = (bf16*)(base + 32 * MB);          // dead after qk-proj
    float* bqk  = (float*)(base + 36 * MB);         // dead after qk-proj
    bf16*  attb = (bf16*)(base + 96 * MB);
    bf16*  W1b  = (bf16*)(base + 96 * MB);          // post-O overlay, re-cast per pass
    bf16*  W2b  = (bf16*)(base + 96 * MB + 524288);
    bf16*  y1c  = (bf16*)(base + 97 * MB);          // 8 MiB per pass
    bf16*  ot   = (bf16*)(base + 160 * MB);
    bf16*  qkt  = (bf16*)(base + 224 * MB);

    dim3 blk(256);
    transpose_cast_x<<<dim3(32, 32, 8), blk, 0, stream>>>(x, xt);
    build_wqk<<<8192, blk, 0, stream>>>(Wq, Wk, bq, bk, Wqk, bqk);
    cast_f2b<<<4096, blk, 0, stream>>>(Wv, Wvb, 8192ll * 1024);

    const long M1 = 1048576, M2 = 2097152, M8 = 8388608;

    // qk_t: M=8192 (b,t), N=2048 (h*256+o), K=1024 — full batch
    gemm_nt<1, 64, 0><<<dim3(16, 64, 1), blk, 0, stream>>>(
        xt, 1024, 0, 0, Wqk, 1024, 0, 0, qkt, 2048, 0, 0, 1024,
        bqk, 0, nullptr, nullptr, 0, nullptr);

    for (int q = 0; q < 2; ++q) {
        const long b0 = (long)q * 4;
        const bf16* xtq = xt + b0 * M1;
        // v(zb,zh;c,s) = Wv[zh](c,ci) . xt(b0+zb;s,ci)^T + bv[zh,c]
        // gemm256: x = zh + 8*ntile (XCD pin), y = m-tile(4), z = zb(4)
        gemm256<0><<<dim3(64, 4, 4), dim3(512), 0, stream>>>(
            Wvb, 1024, 0, M1, xtq, 1024, M1, 0, vbuf, 1024, M8, M1, 1024,
            bv, 1024, nullptr, nullptr, 0);
        // fused E + softmax -> attb bf16 (1024 blocks)
        attn_fused<<<dim3(32, 32, 1), blk, 0, stream>>>(
            qkt + b0 * M2, attb);
        // heads_t(zb,zh;t,c) = gamma[zh]*(attn(t,s).v(c,s)^T) + xt(b0+zb;t,c)
        gemm256<3><<<dim3(64, 4, 4), dim3(512), 0, stream>>>(
            attb, 1024, M8, M1, vbuf, 1024, M8, M1,
            ot, 1024, M8, M1, 1024,
            nullptr, 0, gamma, xtq, 1024);
        // attb dead: cast FC weights into its region (re-done each pass)
        cast_f2b<<<512, blk, 0, stream>>>(W1, W1b, 128 * 1024);
        cast_f2b<<<64, blk, 0, stream>>>(W2, W2b, 128 * 128);
        // y1c = relu(ot . W1^T + b1): M=32768, N=128, K=1024
        gemm_nt<4, 64, 0><<<dim3(1, 256, 1), blk, 0, stream>>>(
            ot, 1024, 0, 0, W1b, 1024, 0, 0, y1c, 128, 0, 0, 1024,
            b1, 0, nullptr, nullptr, 0, nullptr);
        // out = relu(y1c . W2^T + b2) scattered + x (pass-local rows)
        gemm_nt<5, 128, 0><<<dim3(1, 256, 1), blk, 0, stream>>>(
            y1c, 128, 0, 0, W2b, 128, 0, 0, out + b0 * M1, 0, 0, 0, 128,
            b2, 0, nullptr, nullptr, 0, x + b0 * M1);
    }
}

// Round 7
// 652.319 us; speedup vs baseline: 1.0767x; 1.0374x over previous
//
#include <hip/hip_runtime.h>
#include <hip/hip_bf16.h>

typedef __hip_bfloat16 bf16;
typedef __attribute__((ext_vector_type(8))) __bf16 bf16x8;
typedef __attribute__((ext_vector_type(4))) float f32x4;

#define BM 128
#define BN 128

typedef const __attribute__((address_space(1))) void gvoid;
typedef __attribute__((address_space(3))) void lvoid;

// ---------------------------------------------------------------------------
// gemm256 v2: counted-vmcnt ring-pipelined NT GEMM, BK=32, 2 blocks/CU.
// Tile 256x128, 512 thr (8 waves, 4Mx2N, per-wave 64x64). Ring: 3 slots x
// (A 256x32 + B 128x32) bf16 = 72 KB -> 2 blocks/CU (16 waves, stall overlap).
// Pipeline: compute tile t from slot t%3 while t+2's loads fly; vmcnt(3)
// at iter end drains t+1's 3 loads/thread only (T3+T4). 1 barrier/K-tile.
// LDS swizzle: row-pair XOR — chunk c -> p=c>>3, s'=(c&7)^(p&7), m=2p+(s'>>2),
// j=s'&3; read (m,kq) at p*64 + ((kq|((m&1)<<2))^(p&7))*8 -> 2-way banks (free).
// MODE 0: acc + bias[zh*sBiasZ+m] (v-proj); MODE 3: gamma*acc + xt (PV);
// MODE 1: acc + bias[n] (qk-proj, QKLAY=1: nt=blockIdx.x, no slice).
// ---------------------------------------------------------------------------
template<int MODE, int QKLAY>
__global__ __launch_bounds__(512, 4)
void gemm256(const bf16* __restrict__ A, long lda, long sAb, long sAh,
             const bf16* __restrict__ B, long ldb, long sBb, long sBh,
             void* __restrict__ Cv, long ldc, long sCb, long sCh,
             int K,
             const float* __restrict__ bias, long sBiasZ,
             const float* __restrict__ gamma,
             const bf16* __restrict__ xt, long ldxt)
{
    __shared__ bf16 ring[3][(256 + 128) * 32];   // 73728 B
    const int nt4 = QKLAY ? blockIdx.x : (blockIdx.x >> 3);
    const int zh  = QKLAY ? 0 : (blockIdx.x & 7);
    const int zb  = QKLAY ? 0 : blockIdx.z;
    const bf16* Ab = A + (long)zb * sAb + (long)zh * sAh + (long)blockIdx.y * 256 * lda;
    const bf16* Bb = B + (long)zb * sBb + (long)zh * sBh + (long)nt4 * 128 * ldb;
    const int tid = threadIdx.x;
    const int wave = tid >> 6, lane = tid & 63;
    const int col = lane & 15, quad = lane >> 4;
    const int wm = (wave >> 1) * 64, wn = (wave & 1) * 64;

    // staging: A 1024 chunks (2/thread), B 512 chunks (1/thread); 16B each
    const bf16* aAddr[2];
    const bf16* bAddr1;
    int aDst[2], bDst1;
    #pragma unroll
    for (int i = 0; i < 2; ++i) {
        int cbase = i * 512 + wave * 64;         // wave-uniform chunk base
        int c = cbase + lane;
        int p = c >> 3, s = c & 7;
        int sp = s ^ (p & 7);
        int m = 2 * p + (sp >> 2);
        int j = sp & 3;
        aAddr[i] = Ab + (long)m * lda + (j << 3);
        aDst[i] = cbase * 8;
    }
    {
        int cbase = wave * 64;
        int c = cbase + lane;
        int p = c >> 3, s = c & 7;
        int sp = s ^ (p & 7);
        int m = 2 * p + (sp >> 2);
        int j = sp & 3;
        bAddr1 = Bb + (long)m * ldb + (j << 3);
        bDst1 = 8192 + cbase * 8;
    }

    // K-invariant LDS fragment element-offsets (kq = quad, BK=32 -> 1 x-step)
    int offA[4], offB[4];
    #pragma unroll
    for (int mi = 0; mi < 4; ++mi) {
        int m = wm + mi * 16 + col;
        int p = m >> 1;
        int s = (quad | ((m & 1) << 2)) ^ (p & 7);
        offA[mi] = p * 64 + s * 8;
        int n = wn + mi * 16 + col;
        int pn = n >> 1;
        int sn = (quad | ((n & 1) << 2)) ^ (pn & 7);
        offB[mi] = 8192 + pn * 64 + sn * 8;
    }

    f32x4 acc[4][4] = {};

    auto STAGE = [&](int rb) {
        bf16* base = &ring[rb][0];
        #pragma unroll
        for (int i = 0; i < 2; ++i) {
            __builtin_amdgcn_global_load_lds((gvoid*)aAddr[i], (lvoid*)(base + aDst[i]), 16, 0, 0);
            aAddr[i] += 32;
        }
        __builtin_amdgcn_global_load_lds((gvoid*)bAddr1, (lvoid*)(base + bDst1), 16, 0, 0);
        bAddr1 += 32;
    };

    const int NT = K >> 5;                        // 32 K-tiles
    STAGE(0);
    STAGE(1);                                     // 6 loads in flight
    asm volatile("s_waitcnt vmcnt(3)" ::: "memory");  // tile0 landed, tile1 flying
    __builtin_amdgcn_s_barrier();
    __builtin_amdgcn_sched_barrier(0);

    int rc = 0;
    for (int t = 0; t < NT; ++t) {
        int r2 = rc + 2; if (r2 >= 3) r2 -= 3;
        if (t + 2 < NT) STAGE(r2);                // issue tile t+2 early
        const bf16* buf = &ring[rc][0];
        bf16x8 af[4], bfr[4];
        #pragma unroll
        for (int mi = 0; mi < 4; ++mi)
            af[mi] = *(const bf16x8*)(buf + offA[mi]);
        #pragma unroll
        for (int ni = 0; ni < 4; ++ni)
            bfr[ni] = *(const bf16x8*)(buf + offB[ni]);
        #pragma unroll
        for (int mi = 0; mi < 4; ++mi)
            #pragma unroll
            for (int ni = 0; ni < 4; ++ni)
                acc[mi][ni] = __builtin_amdgcn_mfma_f32_16x16x32_bf16(
                    af[mi], bfr[ni], acc[mi][ni], 0, 0, 0);
        if (t + 2 < NT)
            asm volatile("s_waitcnt vmcnt(3)" ::: "memory");   // t+1 landed, t+2 flying
        else if (t + 1 < NT)
            asm volatile("s_waitcnt vmcnt(0)" ::: "memory");   // drain last stage
        if (t + 1 < NT) {
            __builtin_amdgcn_s_barrier();
            __builtin_amdgcn_sched_barrier(0);
        }
        rc = rc + 1; if (rc >= 3) rc -= 3;
    }

    const long m0 = (long)blockIdx.y * 256 + wm;
    const long n0 = (long)nt4 * 128 + wn;
    float g = 0.f;
    if (MODE == 3) g = gamma[zh];
    float bn[4];
    if constexpr (MODE == 1) {
        #pragma unroll
        for (int ni = 0; ni < 4; ++ni)
            bn[ni] = bias[n0 + ni * 16 + col];
    }
    #pragma unroll
    for (int mi = 0; mi < 4; ++mi) {
        #pragma unroll
        for (int ni = 0; ni < 4; ++ni) {
            long mb = m0 + mi * 16 + quad * 4;
            long n  = n0 + ni * 16 + col;
            if constexpr (MODE == 0) {
                bf16* cp = (bf16*)Cv + (long)zb * sCb + (long)zh * sCh + mb * ldc + n;
                const float* bp = bias + zh * sBiasZ + mb;
                #pragma unroll
                for (int r = 0; r < 4; ++r) {
                    *cp = __float2bfloat16(acc[mi][ni][r] + bp[r]);
                    cp += ldc;
                }
            } else if constexpr (MODE == 1) {
                bf16* cp = (bf16*)Cv + mb * ldc + n;
                #pragma unroll
                for (int r = 0; r < 4; ++r) {
                    *cp = __float2bfloat16(acc[mi][ni][r] + bn[ni]);
                    cp += ldc;
                }
            } else {
                bf16* cp = (bf16*)Cv + (long)zb * sCb + (long)zh * sCh + mb * ldc + n;
                const bf16* xp = xt + (long)zb * 1048576 + mb * ldxt + n;
                #pragma unroll
                for (int r = 0; r < 4; ++r) {
                    float xv = __bfloat162float(*xp);
                    *cp = __float2bfloat16(g * acc[mi][ni][r] + xv);
                    cp += ldc;
                    xp += ldxt;
                }
            }
        }
    }
}

// NT GEMM: C[m,n] = sum_k A[m,k] * B[n,k]   (both row-major, K contiguous)
// MODE 4: C bf16 = relu(acc + bias[n])                       (fc1)
// MODE 5: out f32 scatter + residual (m local row; Cv/xf pre-offset per pass)
template<int MODE, int TBK, int LAYOUT>
__global__ __launch_bounds__(256)
void gemm_nt(const bf16* __restrict__ A, long lda, long sAb, long sAh,
             const bf16* __restrict__ B, long ldb, long sBb, long sBh,
             void* __restrict__ Cv, long ldc, long sCb, long sCh,
             int K,
             const float* __restrict__ bias, long sBiasZ,
             const float* __restrict__ gamma,
             const bf16* __restrict__ xt, long ldxt,
             const float* __restrict__ xf)
{
    __shared__ bf16 As[BM * TBK];
    __shared__ bf16 Bs[BN * TBK];
    const int bxt = (LAYOUT == 2) ? (blockIdx.x >> 3) : blockIdx.x;    // n-tile
    const int zb  = (LAYOUT == 2) ? blockIdx.z : (blockIdx.z >> 3);
    const int zh  = (LAYOUT == 2) ? (blockIdx.x & 7) : (blockIdx.z & 7);
    const bf16* Ab = A + (long)zb * sAb + (long)zh * sAh + (long)blockIdx.y * BM * lda;
    const bf16* Bb = B + (long)zb * sBb + (long)zh * sBh + (long)bxt * BN * ldb;
    const int tid  = threadIdx.x;
    const int wave = tid >> 6, lane = tid & 63;
    const int col  = lane & 15, quad = lane >> 4;
    const int wm = (wave & 1) * 64, wn = (wave >> 1) * 64;
    constexpr int CPR = TBK / 8;            // 16B chunks per row
    constexpr int NSLOT = TBK / 16;         // staging slots per operand
    constexpr int NX = TBK / 32;            // kk iterations

    const bf16* aAddr[NSLOT];
    const bf16* bAddr[NSLOT];
    #pragma unroll
    for (int i = 0; i < NSLOT; ++i) {
        int cbase = i * 256 + wave * 64;     // wave-uniform chunk base
        int c = cbase + lane;                // chunk id
        int m = c / CPR;                     // tile row
        int j = c % CPR;                     // chunk slot in row
        int kch = ((j ^ (m & 7)) << 3);      // swizzled k offset (elements)
        aAddr[i] = Ab + (long)m * lda + kch;
        bAddr[i] = Bb + (long)m * ldb + kch;
    }

    int offA[NX][4], offB[NX][4];
    #pragma unroll
    for (int x = 0; x < NX; ++x) {
        int kq = x * 4 + quad;               // (kk>>3)+quad with kk = x*32
        #pragma unroll
        for (int mi = 0; mi < 4; ++mi) {
            int m = wm + mi * 16 + col;
            offA[x][mi] = m * TBK + ((kq ^ (m & 7)) << 3);
            int n = wn + mi * 16 + col;
            offB[x][mi] = n * TBK + ((kq ^ (n & 7)) << 3);
        }
    }

    f32x4 acc[4][4] = {};

    for (int k0 = 0; k0 < K; k0 += TBK) {
        __syncthreads();
        #pragma unroll
        for (int i = 0; i < NSLOT; ++i) {
            int cbase = i * 256 + wave * 64;
            __builtin_amdgcn_global_load_lds(
                (gvoid*)aAddr[i], (lvoid*)(As + cbase * 8), 16, 0, 0);
            __builtin_amdgcn_global_load_lds(
                (gvoid*)bAddr[i], (lvoid*)(Bs + cbase * 8), 16, 0, 0);
            aAddr[i] += TBK;
            bAddr[i] += TBK;
        }
        __syncthreads();
        #pragma unroll
        for (int x = 0; x < NX; ++x) {
            bf16x8 af[4], bfr[4];
            #pragma unroll
            for (int mi = 0; mi < 4; ++mi)
                af[mi] = *(const bf16x8*)(As + offA[x][mi]);
            #pragma unroll
            for (int ni = 0; ni < 4; ++ni)
                bfr[ni] = *(const bf16x8*)(Bs + offB[x][ni]);
            #pragma unroll
            for (int mi = 0; mi < 4; ++mi)
                #pragma unroll
                for (int ni = 0; ni < 4; ++ni)
                    acc[mi][ni] = __builtin_amdgcn_mfma_f32_16x16x32_bf16(
                        af[mi], bfr[ni], acc[mi][ni], 0, 0, 0);
        }
    }

    const long m0 = (long)blockIdx.y * BM + wm;
    const long n0 = (long)bxt * BN + wn;
    float g = 0.f;
    if (MODE == 3) g = gamma[zh];

    float bn[4];
    if constexpr (MODE == 1 || MODE == 4 || MODE == 5) {
        #pragma unroll
        for (int ni = 0; ni < 4; ++ni)
            bn[ni] = bias[n0 + ni * 16 + col];
    }

    #pragma unroll
    for (int mi = 0; mi < 4; ++mi) {
        #pragma unroll
        for (int ni = 0; ni < 4; ++ni) {
            long mb = m0 + mi * 16 + quad * 4;
            long n  = n0 + ni * 16 + col;
            if constexpr (MODE == 0) {
                bf16* cp = (bf16*)Cv + (long)zb * sCb + (long)zh * sCh + mb * ldc + n;
                const float* bp = bias + zh * sBiasZ + mb;
                #pragma unroll
                for (int r = 0; r < 4; ++r) {
                    float v = acc[mi][ni][r] + bp[r];
                    *cp = __float2bfloat16(v);
                    cp += ldc;
                }
            } else if constexpr (MODE == 1) {
                bf16* cp = (bf16*)Cv + mb * ldc + n;
                #pragma unroll
                for (int r = 0; r < 4; ++r) {
                    float v = acc[mi][ni][r] + bn[ni];
                    *cp = __float2bfloat16(v);
                    cp += ldc;
                }
            } else if constexpr (MODE == 3) {
                bf16* cp = (bf16*)Cv + (long)zb * sCb + (long)zh * sCh + mb * ldc + n;
                const bf16* xp = xt + (long)zb * 1048576 + mb * ldxt + n;
                #pragma unroll
                for (int r = 0; r < 4; ++r) {
                    float xv = __bfloat162float(*xp);
                    *cp = __float2bfloat16(g * acc[mi][ni][r] + xv);
                    cp += ldc;
                    xp += ldxt;
                }
            } else if constexpr (MODE == 4) {
                bf16* cp = (bf16*)Cv + mb * ldc + n;
                #pragma unroll
                for (int r = 0; r < 4; ++r) {
                    float v = acc[mi][ni][r] + bn[ni];
                    v = v > 0.f ? v : 0.f;
                    *cp = __float2bfloat16(v);
                    cp += ldc;
                }
            } else {  // MODE 5
                #pragma unroll
                for (int r = 0; r < 4; ++r) {
                    long m = mb + r;
                    float v = acc[mi][ni][r] + bn[ni];
                    v = v > 0.f ? v : 0.f;
                    long bb = m >> 13, h = (m >> 10) & 7, t = m & 1023;
                    long oi = bb * 1048576 + (n * 8 + h) * 1024 + t;
                    ((float*)Cv)[oi] = v + xf[oi];
                }
            }
        }
    }
}

// Fused energy + softmax. Grid: (slices, T/32). Block 256 (4 waves).
__global__ __launch_bounds__(256, 2)
void attn_fused(const bf16* __restrict__ qk, bf16* __restrict__ attn)
{
    constexpr int PAD = 1032;
    __shared__ __align__(16) char smraw[40960];
    __shared__ float red[2][4][32];
    bf16* Qs = (bf16*)smraw;                  // [32][128]
    bf16* Ks = (bf16*)(smraw + 8192);         // [128][128]
    bf16* Sbuf = (bf16*)smraw;                // [16][PAD]

    const int z = blockIdx.x;
    const int zb = z >> 3, zh = z & 7;
    const int t0 = blockIdx.y * 32;
    const int tid = threadIdx.x, w = tid >> 6, lane = tid & 63;
    const int col = lane & 15, quad = lane >> 4;

    const bf16* Qbase = qk + ((long)zb * 1024 + t0) * 2048 + zh * 256;
    const bf16* Kbase = qk + (long)zb * 1024 * 2048 + zh * 256 + 128;

    #pragma unroll
    for (int i = 0; i < 2; ++i) {
        int cbase = i * 256 + w * 64;
        int c = cbase + lane;
        int m = c >> 4, j = c & 15;
        __builtin_amdgcn_global_load_lds(
            (gvoid*)(Qbase + (long)m * 2048 + ((j ^ (m & 7)) << 3)),
            (lvoid*)(Qs + cbase * 8), 16, 0, 0);
    }
    __syncthreads();
    bf16x8 af[2][4];
    #pragma unroll
    for (int mi = 0; mi < 2; ++mi) {
        int m = mi * 16 + col;
        #pragma unroll
        for (int ki = 0; ki < 4; ++ki)
            af[mi][ki] = *(const bf16x8*)(Qs + m * 128 + ((((ki << 2) + quad) ^ (m & 7)) << 3));
    }

    f32x4 acc[2][16] = {};
    #pragma unroll
    for (int si = 0; si < 8; ++si) {
        __syncthreads();
        const bf16* Kb = Kbase + (long)si * 128 * 2048;
        #pragma unroll
        for (int i = 0; i < 8; ++i) {
            int cbase = i * 256 + w * 64;
            int c = cbase + lane;
            int m = c >> 4, j = c & 15;
            __builtin_amdgcn_global_load_lds(
                (gvoid*)(Kb + (long)m * 2048 + ((j ^ (m & 7)) << 3)),
                (lvoid*)(Ks + cbase * 8), 16, 0, 0);
        }
        __syncthreads();
        bf16x8 bfr[2][4];
        #pragma unroll
        for (int ni = 0; ni < 2; ++ni) {
            int n = w * 32 + ni * 16 + col;
            #pragma unroll
            for (int ki = 0; ki < 4; ++ki)
                bfr[ni][ki] = *(const bf16x8*)(Ks + n * 128 + ((((ki << 2) + quad) ^ (n & 7)) << 3));
        }
        #pragma unroll
        for (int ki = 0; ki < 4; ++ki)
            #pragma unroll
            for (int mi = 0; mi < 2; ++mi)
                #pragma unroll
                for (int ni = 0; ni < 2; ++ni)
                    acc[mi][si * 2 + ni] = __builtin_amdgcn_mfma_f32_16x16x32_bf16(
                        af[mi][ki], bfr[ni][ki], acc[mi][si * 2 + ni], 0, 0, 0);
    }

    float rmx[2][4], rinv[2][4];
    #pragma unroll
    for (int mi = 0; mi < 2; ++mi)
        #pragma unroll
        for (int r = 0; r < 4; ++r) {
            float mx = acc[mi][0][r];
            #pragma unroll
            for (int j = 1; j < 16; ++j) mx = fmaxf(mx, acc[mi][j][r]);
            #pragma unroll
            for (int off = 1; off < 16; off <<= 1) mx = fmaxf(mx, __shfl_xor(mx, off, 64));
            rmx[mi][r] = mx;
        }
    if (col == 0) {
        #pragma unroll
        for (int mi = 0; mi < 2; ++mi)
            #pragma unroll
            for (int r = 0; r < 4; ++r)
                red[0][w][mi * 16 + quad * 4 + r] = rmx[mi][r];
    }
    __syncthreads();
    #pragma unroll
    for (int mi = 0; mi < 2; ++mi)
        #pragma unroll
        for (int r = 0; r < 4; ++r) {
            int row = mi * 16 + quad * 4 + r;
            rmx[mi][r] = fmaxf(fmaxf(red[0][0][row], red[0][1][row]),
                               fmaxf(red[0][2][row], red[0][3][row]));
        }
    #pragma unroll
    for (int mi = 0; mi < 2; ++mi)
        #pragma unroll
        for (int r = 0; r < 4; ++r) {
            float s = 0.f;
            #pragma unroll
            for (int j = 0; j < 16; ++j) {
                acc[mi][j][r] = __expf(acc[mi][j][r] - rmx[mi][r]);
                s += acc[mi][j][r];
            }
            #pragma unroll
            for (int off = 1; off < 16; off <<= 1) s += __shfl_xor(s, off, 64);
            rinv[mi][r] = s;
        }
    if (col == 0) {
        #pragma unroll
        for (int mi = 0; mi < 2; ++mi)
            #pragma unroll
            for (int r = 0; r < 4; ++r)
                red[1][w][mi * 16 + quad * 4 + r] = rinv[mi][r];
    }
    __syncthreads();
    #pragma unroll
    for (int mi = 0; mi < 2; ++mi)
        #pragma unroll
        for (int r = 0; r < 4; ++r) {
            int row = mi * 16 + quad * 4 + r;
            float s4 = red[1][0][row] + red[1][1][row] + red[1][2][row] + red[1][3][row];
            rinv[mi][r] = 1.0f / s4;
        }

    bf16* dst = attn + ((long)(zb * 8 + zh)) * 1048576 + (long)t0 * 1024;
    #pragma unroll
    for (int mi = 0; mi < 2; ++mi) {
        __syncthreads();
        #pragma unroll
        for (int j = 0; j < 16; ++j) {
            int colb = (j >> 1) * 128 + w * 32 + (j & 1) * 16 + col;
            #pragma unroll
            for (int r = 0; r < 4; ++r) {
                int rowh = quad * 4 + r;
                Sbuf[rowh * PAD + colb] = __float2bfloat16(acc[mi][j][r] * rinv[mi][r]);
            }
        }
        __syncthreads();
        #pragma unroll
        for (int i = 0; i < 8; ++i) {
            int c = i * 256 + tid;             // 16 rows x 128 chunks
            int rowh = c >> 7, jj = c & 127;
            bf16x8 vv = *(const bf16x8*)(Sbuf + rowh * PAD + jj * 8);
            *(bf16x8*)(dst + (long)(mi * 16 + rowh) * 1024 + jj * 8) = vv;
        }
    }
}

// x (B,C,T) f32 -> xt (B,T,C) bf16, 32x32 LDS tiles
__global__ __launch_bounds__(256)
void transpose_cast_x(const float* __restrict__ x, bf16* __restrict__ xt)
{
    __shared__ float tile[32][33];
    int b = blockIdx.z;
    int c0 = blockIdx.y * 32, t0 = blockIdx.x * 32;
    int tx = threadIdx.x & 31, ty = threadIdx.x >> 5;  // ty 0..7
    const float* xb = x + (long)b * 1024 * 1024;
    #pragma unroll
    for (int i = 0; i < 4; ++i) {
        int c = ty + i * 8;
        tile[c][tx] = xb[(long)(c0 + c) * 1024 + t0 + tx];
    }
    __syncthreads();
    bf16* xtb = xt + (long)b * 1024 * 1024;
    #pragma unroll
    for (int i = 0; i < 4; ++i) {
        int t = ty + i * 8;
        xtb[(long)(t0 + t) * 1024 + c0 + tx] = __float2bfloat16(tile[tx][t]);
    }
}

__global__ __launch_bounds__(256)
void cast_f2b(const float* __restrict__ in, bf16* __restrict__ out, long n)
{
    long i = (long)blockIdx.x * 256 + threadIdx.x;
    long stride = (long)gridDim.x * 256;
    for (; i < n; i += stride) out[i] = __float2bfloat16(in[i]);
}

// Build stacked qk weight (2048 x 1024 bf16)
__global__ __launch_bounds__(256)
void build_wqk(const float* __restrict__ Wq, const float* __restrict__ Wk,
               const float* __restrict__ bq, const float* __restrict__ bk,
               bf16* __restrict__ Wqk, float* __restrict__ biasqk)
{
    long i = (long)blockIdx.x * 256 + threadIdx.x;   // 2048*1024 total
    long r = i >> 10, c = i & 1023;
    long h = r >> 8, rr = r & 255;
    float v = (rr < 128) ? Wq[(h * 128 + rr) * 1024 + c]
                         : Wk[(h * 128 + (rr - 128)) * 1024 + c];
    Wqk[i] = __float2bfloat16(v);
    if (c == 0)
        biasqk[r] = (rr < 128) ? bq[h * 128 + rr] : bk[h * 128 + rr - 128];
}

extern "C" void kernel_launch(void* const* d_in, const int* in_sizes, int n_in,
                              void* d_out, int out_size, void* d_ws, size_t ws_size,
                              hipStream_t stream)
{
    const float* x     = (const float*)d_in[0];
    const float* Wq    = (const float*)d_in[1];
    const float* bq    = (const float*)d_in[2];
    const float* Wk    = (const float*)d_in[3];
    const float* bk    = (const float*)d_in[4];
    const float* Wv    = (const float*)d_in[5];
    const float* bv    = (const float*)d_in[6];
    const float* gamma = (const float*)d_in[7];
    const float* W1    = (const float*)d_in[8];
    const float* b1    = (const float*)d_in[9];
    const float* W2    = (const float*)d_in[10];
    const float* b2    = (const float*)d_in[11];
    float* out = (float*)d_out;

    char* base = (char*)d_ws;
    const long MB = 1048576;
    bf16*  xt   = (bf16*)(base);
    bf16*  Wvb  = (bf16*)(base + 16 * MB);
    bf16*  vbuf = (bf16*)(base + 32 * MB);
    bf16*  Wqk  = (bf16*)(base + 32 * MB);          // dead after qk-proj
    float* bqk  = (float*)(base + 36 * MB);         // dead after qk-proj
    bf16*  attb = (bf16*)(base + 96 * MB);
    bf16*  W1b  = (bf16*)(base + 96 * MB);          // post-O overlay, re-cast per pass
    bf16*  W2b  = (bf16*)(base + 96 * MB + 524288);
    bf16*  y1c  = (bf16*)(base + 97 * MB);          // 8 MiB per pass
    bf16*  ot   = (bf16*)(base + 160 * MB);
    bf16*  qkt  = (bf16*)(base + 224 * MB);

    dim3 blk(256);
    transpose_cast_x<<<dim3(32, 32, 8), blk, 0, stream>>>(x, xt);
    build_wqk<<<8192, blk, 0, stream>>>(Wq, Wk, bq, bk, Wqk, bqk);
    cast_f2b<<<4096, blk, 0, stream>>>(Wv, Wvb, 8192ll * 1024);

    const long M1 = 1048576, M2 = 2097152, M8 = 8388608;

    // qk_t: M=8192 (b,t), N=2048 (h*256+o), K=1024 — gemm256 QKLAY (512 blocks)
    gemm256<1, 1><<<dim3(16, 32, 1), dim3(512), 0, stream>>>(
        xt, 1024, 0, 0, Wqk, 1024, 0, 0, qkt, 2048, 0, 0, 1024,
        bqk, 0, nullptr, nullptr, 0);

    for (int q = 0; q < 2; ++q) {
        const long b0 = (long)q * 4;
        const bf16* xtq = xt + b0 * M1;
        // v(zb,zh;c,s) = Wv[zh](c,ci) . xt(b0+zb;s,ci)^T + bv[zh,c]
        // gemm256: x = zh + 8*ntile (XCD pin), y = m-tile(4), z = zb(4)
        gemm256<0, 0><<<dim3(64, 4, 4), dim3(512), 0, stream>>>(
            Wvb, 1024, 0, M1, xtq, 1024, M1, 0, vbuf, 1024, M8, M1, 1024,
            bv, 1024, nullptr, nullptr, 0);
        // fused E + softmax -> attb bf16 (1024 blocks)
        attn_fused<<<dim3(32, 32, 1), blk, 0, stream>>>(
            qkt + b0 * M2, attb);
        // heads_t(zb,zh;t,c) = gamma[zh]*(attn(t,s).v(c,s)^T) + xt(b0+zb;t,c)
        gemm256<3, 0><<<dim3(64, 4, 4), dim3(512), 0, stream>>>(
            attb, 1024, M8, M1, vbuf, 1024, M8, M1,
            ot, 1024, M8, M1, 1024,
            nullptr, 0, gamma, xtq, 1024);
        // attb dead: cast FC weights into its region (re-done each pass)
        cast_f2b<<<512, blk, 0, stream>>>(W1, W1b, 128 * 1024);
        cast_f2b<<<64, blk, 0, stream>>>(W2, W2b, 128 * 128);
        // y1c = relu(ot . W1^T + b1): M=32768, N=128, K=1024
        gemm_nt<4, 64, 0><<<dim3(1, 256, 1), blk, 0, stream>>>(
            ot, 1024, 0, 0, W1b, 1024, 0, 0, y1c, 128, 0, 0, 1024,
            b1, 0, nullptr, nullptr, 0, nullptr);
        // out = relu(y1c . W2^T + b2) scattered + x (pass-local rows)
        gemm_nt<5, 128, 0><<<dim3(1, 256, 1), blk, 0, stream>>>(
            y1c, 128, 0, 0, W2b, 128, 0, 0, out + b0 * M1, 0, 0, 0, 128,
            b2, 0, nullptr, nullptr, 0, x + b0 * M1);
    }
}

// Round 8
// 637.776 us; speedup vs baseline: 1.1013x; 1.0228x over previous
//
#include <hip/hip_runtime.h>
#include <hip/hip_bf16.h>

typedef __hip_bfloat16 bf16;
typedef __attribute__((ext_vector_type(8))) __bf16 bf16x8;
typedef __attribute__((ext_vector_type(4))) float f32x4;

#define BM 128
#define BN 128

typedef const __attribute__((address_space(1))) void gvoid;
typedef __attribute__((address_space(3))) void lvoid;

// ---------------------------------------------------------------------------
// gemm256 v3: counted-vmcnt ring-pipelined NT GEMM, BK=32, 2 blocks/CU,
// 4 waves x (64M x 128N) per wave (acc 4x8) — R8 reshape: LDS reads per
// block-K-tile 64 -> 48 b128 (reads/MFMA 0.5 -> 0.375), making the matrix
// pipe (1242 cyc/pair) the binder instead of the LDS pipe (was ~1920).
// Ring: 3 slots x (A 256x32 + B 128x32) bf16 = 72 KB -> 2 blocks/CU.
// Pipeline: compute tile t from slot t%3 while t+2's loads fly; vmcnt(6)
// BEFORE the barrier drains t+1's 6 loads/thread only (cross-wave safety:
// every wave past barrier => every wave's t+1 loads landed). 1 barrier/K-tile.
// LDS swizzle: row-pair XOR (verified 0-conflict R6/R7) — chunk c -> p=c>>3,
// s'=(c&7)^(p&7), m=2p+(s'>>2), j=s'&3; read (m,quad) at p*64+((quad|((m&1)<<2))^(p&7))*8.
// MODE 0: acc + bias[zh*sBiasZ+m] (v-proj); MODE 3: gamma*acc + xt (PV);
// MODE 1: acc + bias[n] (qk-proj, QKLAY=1: nt=blockIdx.x, no slice).
// ---------------------------------------------------------------------------
template<int MODE, int QKLAY>
__global__ __launch_bounds__(256, 2)
void gemm256(const bf16* __restrict__ A, long lda, long sAb, long sAh,
             const bf16* __restrict__ B, long ldb, long sBb, long sBh,
             void* __restrict__ Cv, long ldc, long sCb, long sCh,
             int K,
             const float* __restrict__ bias, long sBiasZ,
             const float* __restrict__ gamma,
             const bf16* __restrict__ xt, long ldxt)
{
    __shared__ bf16 ring[3][(256 + 128) * 32];   // 73728 B
    const int nt4 = QKLAY ? blockIdx.x : (blockIdx.x >> 3);
    const int zh  = QKLAY ? 0 : (blockIdx.x & 7);
    const int zb  = QKLAY ? 0 : blockIdx.z;
    const bf16* Ab = A + (long)zb * sAb + (long)zh * sAh + (long)blockIdx.y * 256 * lda;
    const bf16* Bb = B + (long)zb * sBb + (long)zh * sBh + (long)nt4 * 128 * ldb;
    const int tid = threadIdx.x;
    const int wave = tid >> 6, lane = tid & 63;
    const int col = lane & 15, quad = lane >> 4;
    const int wm = wave * 64;                    // per-wave 64 rows, full 128 cols

    // staging: A 1024 chunks (4/thread), B 512 chunks (2/thread); 16B each
    const bf16* aAddr[4];
    const bf16* bAddr[2];
    int aDst[4], bDst[2];
    #pragma unroll
    for (int i = 0; i < 4; ++i) {
        int cbase = i * 256 + wave * 64;         // wave-uniform chunk base
        int c = cbase + lane;
        int p = c >> 3;
        int sp = (c & 7) ^ (p & 7);
        int m = 2 * p + (sp >> 2);
        int j = sp & 3;
        aAddr[i] = Ab + (long)m * lda + (j << 3);
        aDst[i] = cbase * 8;
    }
    #pragma unroll
    for (int i = 0; i < 2; ++i) {
        int cbase = i * 256 + wave * 64;
        int c = cbase + lane;
        int p = c >> 3;
        int sp = (c & 7) ^ (p & 7);
        int m = 2 * p + (sp >> 2);
        int j = sp & 3;
        bAddr[i] = Bb + (long)m * ldb + (j << 3);
        bDst[i] = 8192 + cbase * 8;              // B region after A (256*32 elems)
    }

    // K-invariant LDS fragment element-offsets (kq = quad)
    int offA[4], offB[8];
    #pragma unroll
    for (int mi = 0; mi < 4; ++mi) {
        int m = wm + mi * 16 + col;
        int p = m >> 1;
        int s = (quad | ((m & 1) << 2)) ^ (p & 7);
        offA[mi] = p * 64 + s * 8;
    }
    #pragma unroll
    for (int ni = 0; ni < 8; ++ni) {
        int n = ni * 16 + col;
        int pn = n >> 1;
        int sn = (quad | ((n & 1) << 2)) ^ (pn & 7);
        offB[ni] = 8192 + pn * 64 + sn * 8;
    }

    f32x4 acc[4][8] = {};

    auto STAGE = [&](int rb) {
        bf16* base = &ring[rb][0];
        #pragma unroll
        for (int i = 0; i < 4; ++i) {
            __builtin_amdgcn_global_load_lds((gvoid*)aAddr[i], (lvoid*)(base + aDst[i]), 16, 0, 0);
            aAddr[i] += 32;
        }
        #pragma unroll
        for (int i = 0; i < 2; ++i) {
            __builtin_amdgcn_global_load_lds((gvoid*)bAddr[i], (lvoid*)(base + bDst[i]), 16, 0, 0);
            bAddr[i] += 32;
        }
    };

    const int NT = K >> 5;                        // 32 K-tiles
    STAGE(0);
    STAGE(1);                                     // 12 loads in flight
    asm volatile("s_waitcnt vmcnt(6)" ::: "memory");  // tile0 landed, tile1 flying
    __builtin_amdgcn_s_barrier();
    __builtin_amdgcn_sched_barrier(0);

    int rc = 0;
    for (int t = 0; t < NT; ++t) {
        int r2 = rc + 2; if (r2 >= 3) r2 -= 3;
        if (t + 2 < NT) STAGE(r2);                // issue tile t+2 early
        const bf16* buf = &ring[rc][0];
        bf16x8 af[4], bfr[8];
        #pragma unroll
        for (int mi = 0; mi < 4; ++mi)
            af[mi] = *(const bf16x8*)(buf + offA[mi]);
        #pragma unroll
        for (int ni = 0; ni < 8; ++ni)
            bfr[ni] = *(const bf16x8*)(buf + offB[ni]);
        #pragma unroll
        for (int mi = 0; mi < 4; ++mi)
            #pragma unroll
            for (int ni = 0; ni < 8; ++ni)
                acc[mi][ni] = __builtin_amdgcn_mfma_f32_16x16x32_bf16(
                    af[mi], bfr[ni], acc[mi][ni], 0, 0, 0);
        if (t + 2 < NT)
            asm volatile("s_waitcnt vmcnt(6)" ::: "memory");   // t+1 landed, t+2 flying
        else if (t + 1 < NT)
            asm volatile("s_waitcnt vmcnt(0)" ::: "memory");   // drain last stage
        if (t + 1 < NT) {
            __builtin_amdgcn_s_barrier();
            __builtin_amdgcn_sched_barrier(0);
        }
        rc = rc + 1; if (rc >= 3) rc -= 3;
    }

    const long m0 = (long)blockIdx.y * 256 + wm;
    const long n0 = (long)nt4 * 128;
    float g = 0.f;
    if (MODE == 3) g = gamma[zh];
    float bn[8];
    if constexpr (MODE == 1) {
        #pragma unroll
        for (int ni = 0; ni < 8; ++ni)
            bn[ni] = bias[n0 + ni * 16 + col];
    }
    #pragma unroll
    for (int mi = 0; mi < 4; ++mi) {
        #pragma unroll
        for (int ni = 0; ni < 8; ++ni) {
            long mb = m0 + mi * 16 + quad * 4;
            long n  = n0 + ni * 16 + col;
            if constexpr (MODE == 0) {
                bf16* cp = (bf16*)Cv + (long)zb * sCb + (long)zh * sCh + mb * ldc + n;
                const float* bp = bias + zh * sBiasZ + mb;
                #pragma unroll
                for (int r = 0; r < 4; ++r) {
                    *cp = __float2bfloat16(acc[mi][ni][r] + bp[r]);
                    cp += ldc;
                }
            } else if constexpr (MODE == 1) {
                bf16* cp = (bf16*)Cv + mb * ldc + n;
                #pragma unroll
                for (int r = 0; r < 4; ++r) {
                    *cp = __float2bfloat16(acc[mi][ni][r] + bn[ni]);
                    cp += ldc;
                }
            } else {
                bf16* cp = (bf16*)Cv + (long)zb * sCb + (long)zh * sCh + mb * ldc + n;
                const bf16* xp = xt + (long)zb * 1048576 + mb * ldxt + n;
                #pragma unroll
                for (int r = 0; r < 4; ++r) {
                    float xv = __bfloat162float(*xp);
                    *cp = __float2bfloat16(g * acc[mi][ni][r] + xv);
                    cp += ldc;
                    xp += ldxt;
                }
            }
        }
    }
}

// NT GEMM: C[m,n] = sum_k A[m,k] * B[n,k]   (both row-major, K contiguous)
// MODE 4: C bf16 = relu(acc + bias[n])                       (fc1)
// MODE 5: out f32 scatter + residual (m local row; Cv/xf pre-offset per pass)
template<int MODE, int TBK, int LAYOUT>
__global__ __launch_bounds__(256)
void gemm_nt(const bf16* __restrict__ A, long lda, long sAb, long sAh,
             const bf16* __restrict__ B, long ldb, long sBb, long sBh,
             void* __restrict__ Cv, long ldc, long sCb, long sCh,
             int K,
             const float* __restrict__ bias, long sBiasZ,
             const float* __restrict__ gamma,
             const bf16* __restrict__ xt, long ldxt,
             const float* __restrict__ xf)
{
    __shared__ bf16 As[BM * TBK];
    __shared__ bf16 Bs[BN * TBK];
    const int bxt = (LAYOUT == 2) ? (blockIdx.x >> 3) : blockIdx.x;    // n-tile
    const int zb  = (LAYOUT == 2) ? blockIdx.z : (blockIdx.z >> 3);
    const int zh  = (LAYOUT == 2) ? (blockIdx.x & 7) : (blockIdx.z & 7);
    const bf16* Ab = A + (long)zb * sAb + (long)zh * sAh + (long)blockIdx.y * BM * lda;
    const bf16* Bb = B + (long)zb * sBb + (long)zh * sBh + (long)bxt * BN * ldb;
    const int tid  = threadIdx.x;
    const int wave = tid >> 6, lane = tid & 63;
    const int col  = lane & 15, quad = lane >> 4;
    const int wm = (wave & 1) * 64, wn = (wave >> 1) * 64;
    constexpr int CPR = TBK / 8;            // 16B chunks per row
    constexpr int NSLOT = TBK / 16;         // staging slots per operand
    constexpr int NX = TBK / 32;            // kk iterations

    const bf16* aAddr[NSLOT];
    const bf16* bAddr[NSLOT];
    #pragma unroll
    for (int i = 0; i < NSLOT; ++i) {
        int cbase = i * 256 + wave * 64;     // wave-uniform chunk base
        int c = cbase + lane;                // chunk id
        int m = c / CPR;                     // tile row
        int j = c % CPR;                     // chunk slot in row
        int kch = ((j ^ (m & 7)) << 3);      // swizzled k offset (elements)
        aAddr[i] = Ab + (long)m * lda + kch;
        bAddr[i] = Bb + (long)m * ldb + kch;
    }

    int offA[NX][4], offB[NX][4];
    #pragma unroll
    for (int x = 0; x < NX; ++x) {
        int kq = x * 4 + quad;               // (kk>>3)+quad with kk = x*32
        #pragma unroll
        for (int mi = 0; mi < 4; ++mi) {
            int m = wm + mi * 16 + col;
            offA[x][mi] = m * TBK + ((kq ^ (m & 7)) << 3);
            int n = wn + mi * 16 + col;
            offB[x][mi] = n * TBK + ((kq ^ (n & 7)) << 3);
        }
    }

    f32x4 acc[4][4] = {};

    for (int k0 = 0; k0 < K; k0 += TBK) {
        __syncthreads();
        #pragma unroll
        for (int i = 0; i < NSLOT; ++i) {
            int cbase = i * 256 + wave * 64;
            __builtin_amdgcn_global_load_lds(
                (gvoid*)aAddr[i], (lvoid*)(As + cbase * 8), 16, 0, 0);
            __builtin_amdgcn_global_load_lds(
                (gvoid*)bAddr[i], (lvoid*)(Bs + cbase * 8), 16, 0, 0);
            aAddr[i] += TBK;
            bAddr[i] += TBK;
        }
        __syncthreads();
        #pragma unroll
        for (int x = 0; x < NX; ++x) {
            bf16x8 af[4], bfr[4];
            #pragma unroll
            for (int mi = 0; mi < 4; ++mi)
                af[mi] = *(const bf16x8*)(As + offA[x][mi]);
            #pragma unroll
            for (int ni = 0; ni < 4; ++ni)
                bfr[ni] = *(const bf16x8*)(Bs + offB[x][ni]);
            #pragma unroll
            for (int mi = 0; mi < 4; ++mi)
                #pragma unroll
                for (int ni = 0; ni < 4; ++ni)
                    acc[mi][ni] = __builtin_amdgcn_mfma_f32_16x16x32_bf16(
                        af[mi], bfr[ni], acc[mi][ni], 0, 0, 0);
        }
    }

    const long m0 = (long)blockIdx.y * BM + wm;
    const long n0 = (long)bxt * BN + wn;
    float g = 0.f;
    if (MODE == 3) g = gamma[zh];

    float bn[4];
    if constexpr (MODE == 1 || MODE == 4 || MODE == 5) {
        #pragma unroll
        for (int ni = 0; ni < 4; ++ni)
            bn[ni] = bias[n0 + ni * 16 + col];
    }

    #pragma unroll
    for (int mi = 0; mi < 4; ++mi) {
        #pragma unroll
        for (int ni = 0; ni < 4; ++ni) {
            long mb = m0 + mi * 16 + quad * 4;
            long n  = n0 + ni * 16 + col;
            if constexpr (MODE == 0) {
                bf16* cp = (bf16*)Cv + (long)zb * sCb + (long)zh * sCh + mb * ldc + n;
                const float* bp = bias + zh * sBiasZ + mb;
                #pragma unroll
                for (int r = 0; r < 4; ++r) {
                    float v = acc[mi][ni][r] + bp[r];
                    *cp = __float2bfloat16(v);
                    cp += ldc;
                }
            } else if constexpr (MODE == 1) {
                bf16* cp = (bf16*)Cv + mb * ldc + n;
                #pragma unroll
                for (int r = 0; r < 4; ++r) {
                    float v = acc[mi][ni][r] + bn[ni];
                    *cp = __float2bfloat16(v);
                    cp += ldc;
                }
            } else if constexpr (MODE == 3) {
                bf16* cp = (bf16*)Cv + (long)zb * sCb + (long)zh * sCh + mb * ldc + n;
                const bf16* xp = xt + (long)zb * 1048576 + mb * ldxt + n;
                #pragma unroll
                for (int r = 0; r < 4; ++r) {
                    float xv = __bfloat162float(*xp);
                    *cp = __float2bfloat16(g * acc[mi][ni][r] + xv);
                    cp += ldc;
                    xp += ldxt;
                }
            } else if constexpr (MODE == 4) {
                bf16* cp = (bf16*)Cv + mb * ldc + n;
                #pragma unroll
                for (int r = 0; r < 4; ++r) {
                    float v = acc[mi][ni][r] + bn[ni];
                    v = v > 0.f ? v : 0.f;
                    *cp = __float2bfloat16(v);
                    cp += ldc;
                }
            } else {  // MODE 5
                #pragma unroll
                for (int r = 0; r < 4; ++r) {
                    long m = mb + r;
                    float v = acc[mi][ni][r] + bn[ni];
                    v = v > 0.f ? v : 0.f;
                    long bb = m >> 13, h = (m >> 10) & 7, t = m & 1023;
                    long oi = bb * 1048576 + (n * 8 + h) * 1024 + t;
                    ((float*)Cv)[oi] = v + xf[oi];
                }
            }
        }
    }
}

// Fused energy + softmax. Grid: (slices, T/32). Block 256 (4 waves).
__global__ __launch_bounds__(256, 2)
void attn_fused(const bf16* __restrict__ qk, bf16* __restrict__ attn)
{
    constexpr int PAD = 1032;
    __shared__ __align__(16) char smraw[40960];
    __shared__ float red[2][4][32];
    bf16* Qs = (bf16*)smraw;                  // [32][128]
    bf16* Ks = (bf16*)(smraw + 8192);         // [128][128]
    bf16* Sbuf = (bf16*)smraw;                // [16][PAD]

    const int z = blockIdx.x;
    const int zb = z >> 3, zh = z & 7;
    const int t0 = blockIdx.y * 32;
    const int tid = threadIdx.x, w = tid >> 6, lane = tid & 63;
    const int col = lane & 15, quad = lane >> 4;

    const bf16* Qbase = qk + ((long)zb * 1024 + t0) * 2048 + zh * 256;
    const bf16* Kbase = qk + (long)zb * 1024 * 2048 + zh * 256 + 128;

    #pragma unroll
    for (int i = 0; i < 2; ++i) {
        int cbase = i * 256 + w * 64;
        int c = cbase + lane;
        int m = c >> 4, j = c & 15;
        __builtin_amdgcn_global_load_lds(
            (gvoid*)(Qbase + (long)m * 2048 + ((j ^ (m & 7)) << 3)),
            (lvoid*)(Qs + cbase * 8), 16, 0, 0);
    }
    __syncthreads();
    bf16x8 af[2][4];
    #pragma unroll
    for (int mi = 0; mi < 2; ++mi) {
        int m = mi * 16 + col;
        #pragma unroll
        for (int ki = 0; ki < 4; ++ki)
            af[mi][ki] = *(const bf16x8*)(Qs + m * 128 + ((((ki << 2) + quad) ^ (m & 7)) << 3));
    }

    f32x4 acc[2][16] = {};
    #pragma unroll
    for (int si = 0; si < 8; ++si) {
        __syncthreads();
        const bf16* Kb = Kbase + (long)si * 128 * 2048;
        #pragma unroll
        for (int i = 0; i < 8; ++i) {
            int cbase = i * 256 + w * 64;
            int c = cbase + lane;
            int m = c >> 4, j = c & 15;
            __builtin_amdgcn_global_load_lds(
                (gvoid*)(Kb + (long)m * 2048 + ((j ^ (m & 7)) << 3)),
                (lvoid*)(Ks + cbase * 8), 16, 0, 0);
        }
        __syncthreads();
        bf16x8 bfr[2][4];
        #pragma unroll
        for (int ni = 0; ni < 2; ++ni) {
            int n = w * 32 + ni * 16 + col;
            #pragma unroll
            for (int ki = 0; ki < 4; ++ki)
                bfr[ni][ki] = *(const bf16x8*)(Ks + n * 128 + ((((ki << 2) + quad) ^ (n & 7)) << 3));
        }
        #pragma unroll
        for (int ki = 0; ki < 4; ++ki)
            #pragma unroll
            for (int mi = 0; mi < 2; ++mi)
                #pragma unroll
                for (int ni = 0; ni < 2; ++ni)
                    acc[mi][si * 2 + ni] = __builtin_amdgcn_mfma_f32_16x16x32_bf16(
                        af[mi][ki], bfr[ni][ki], acc[mi][si * 2 + ni], 0, 0, 0);
    }

    float rmx[2][4], rinv[2][4];
    #pragma unroll
    for (int mi = 0; mi < 2; ++mi)
        #pragma unroll
        for (int r = 0; r < 4; ++r) {
            float mx = acc[mi][0][r];
            #pragma unroll
            for (int j = 1; j < 16; ++j) mx = fmaxf(mx, acc[mi][j][r]);
            #pragma unroll
            for (int off = 1; off < 16; off <<= 1) mx = fmaxf(mx, __shfl_xor(mx, off, 64));
            rmx[mi][r] = mx;
        }
    if (col == 0) {
        #pragma unroll
        for (int mi = 0; mi < 2; ++mi)
            #pragma unroll
            for (int r = 0; r < 4; ++r)
                red[0][w][mi * 16 + quad * 4 + r] = rmx[mi][r];
    }
    __syncthreads();
    #pragma unroll
    for (int mi = 0; mi < 2; ++mi)
        #pragma unroll
        for (int r = 0; r < 4; ++r) {
            int row = mi * 16 + quad * 4 + r;
            rmx[mi][r] = fmaxf(fmaxf(red[0][0][row], red[0][1][row]),
                               fmaxf(red[0][2][row], red[0][3][row]));
        }
    #pragma unroll
    for (int mi = 0; mi < 2; ++mi)
        #pragma unroll
        for (int r = 0; r < 4; ++r) {
            float s = 0.f;
            #pragma unroll
            for (int j = 0; j < 16; ++j) {
                acc[mi][j][r] = __expf(acc[mi][j][r] - rmx[mi][r]);
                s += acc[mi][j][r];
            }
            #pragma unroll
            for (int off = 1; off < 16; off <<= 1) s += __shfl_xor(s, off, 64);
            rinv[mi][r] = s;
        }
    if (col == 0) {
        #pragma unroll
        for (int mi = 0; mi < 2; ++mi)
            #pragma unroll
            for (int r = 0; r < 4; ++r)
                red[1][w][mi * 16 + quad * 4 + r] = rinv[mi][r];
    }
    __syncthreads();
    #pragma unroll
    for (int mi = 0; mi < 2; ++mi)
        #pragma unroll
        for (int r = 0; r < 4; ++r) {
            int row = mi * 16 + quad * 4 + r;
            float s4 = red[1][0][row] + red[1][1][row] + red[1][2][row] + red[1][3][row];
            rinv[mi][r] = 1.0f / s4;
        }

    bf16* dst = attn + ((long)(zb * 8 + zh)) * 1048576 + (long)t0 * 1024;
    #pragma unroll
    for (int mi = 0; mi < 2; ++mi) {
        __syncthreads();
        #pragma unroll
        for (int j = 0; j < 16; ++j) {
            int colb = (j >> 1) * 128 + w * 32 + (j & 1) * 16 + col;
            #pragma unroll
            for (int r = 0; r < 4; ++r) {
                int rowh = quad * 4 + r;
                Sbuf[rowh * PAD + colb] = __float2bfloat16(acc[mi][j][r] * rinv[mi][r]);
            }
        }
        __syncthreads();
        #pragma unroll
        for (int i = 0; i < 8; ++i) {
            int c = i * 256 + tid;             // 16 rows x 128 chunks
            int rowh = c >> 7, jj = c & 127;
            bf16x8 vv = *(const bf16x8*)(Sbuf + rowh * PAD + jj * 8);
            *(bf16x8*)(dst + (long)(mi * 16 + rowh) * 1024 + jj * 8) = vv;
        }
    }
}

// x (B,C,T) f32 -> xt (B,T,C) bf16, 32x32 LDS tiles
__global__ __launch_bounds__(256)
void transpose_cast_x(const float* __restrict__ x, bf16* __restrict__ xt)
{
    __shared__ float tile[32][33];
    int b = blockIdx.z;
    int c0 = blockIdx.y * 32, t0 = blockIdx.x * 32;
    int tx = threadIdx.x & 31, ty = threadIdx.x >> 5;  // ty 0..7
    const float* xb = x + (long)b * 1024 * 1024;
    #pragma unroll
    for (int i = 0; i < 4; ++i) {
        int c = ty + i * 8;
        tile[c][tx] = xb[(long)(c0 + c) * 1024 + t0 + tx];
    }
    __syncthreads();
    bf16* xtb = xt + (long)b * 1024 * 1024;
    #pragma unroll
    for (int i = 0; i < 4; ++i) {
        int t = ty + i * 8;
        xtb[(long)(t0 + t) * 1024 + c0 + tx] = __float2bfloat16(tile[tx][t]);
    }
}

__global__ __launch_bounds__(256)
void cast_f2b(const float* __restrict__ in, bf16* __restrict__ out, long n)
{
    long i = (long)blockIdx.x * 256 + threadIdx.x;
    long stride = (long)gridDim.x * 256;
    for (; i < n; i += stride) out[i] = __float2bfloat16(in[i]);
}

// Build stacked qk weight (2048 x 1024 bf16)
__global__ __launch_bounds__(256)
void build_wqk(const float* __restrict__ Wq, const float* __restrict__ Wk,
               const float* __restrict__ bq, const float* __restrict__ bk,
               bf16* __restrict__ Wqk, float* __restrict__ biasqk)
{
    long i = (long)blockIdx.x * 256 + threadIdx.x;   // 2048*1024 total
    long r = i >> 10, c = i & 1023;
    long h = r >> 8, rr = r & 255;
    float v = (rr < 128) ? Wq[(h * 128 + rr) * 1024 + c]
                         : Wk[(h * 128 + (rr - 128)) * 1024 + c];
    Wqk[i] = __float2bfloat16(v);
    if (c == 0)
        biasqk[r] = (rr < 128) ? bq[h * 128 + rr] : bk[h * 128 + rr - 128];
}

extern "C" void kernel_launch(void* const* d_in, const int* in_sizes, int n_in,
                              void* d_out, int out_size, void* d_ws, size_t ws_size,
                              hipStream_t stream)
{
    const float* x     = (const float*)d_in[0];
    const float* Wq    = (const float*)d_in[1];
    const float* bq    = (const float*)d_in[2];
    const float* Wk    = (const float*)d_in[3];
    const float* bk    = (const float*)d_in[4];
    const float* Wv    = (const float*)d_in[5];
    const float* bv    = (const float*)d_in[6];
    const float* gamma = (const float*)d_in[7];
    const float* W1    = (const float*)d_in[8];
    const float* b1    = (const float*)d_in[9];
    const float* W2    = (const float*)d_in[10];
    const float* b2    = (const float*)d_in[11];
    float* out = (float*)d_out;

    char* base = (char*)d_ws;
    const long MB = 1048576;
    bf16*  xt   = (bf16*)(base);
    bf16*  Wvb  = (bf16*)(base + 16 * MB);
    bf16*  vbuf = (bf16*)(base + 32 * MB);
    bf16*  Wqk  = (bf16*)(base + 32 * MB);          // dead after qk-proj
    float* bqk  = (float*)(base + 36 * MB);         // dead after qk-proj
    bf16*  attb = (bf16*)(base + 96 * MB);
    bf16*  W1b  = (bf16*)(base + 96 * MB);          // post-O overlay, re-cast per pass
    bf16*  W2b  = (bf16*)(base + 96 * MB + 524288);
    bf16*  y1c  = (bf16*)(base + 97 * MB);          // 8 MiB per pass
    bf16*  ot   = (bf16*)(base + 160 * MB);
    bf16*  qkt  = (bf16*)(base + 224 * MB);

    dim3 blk(256);
    transpose_cast_x<<<dim3(32, 32, 8), blk, 0, stream>>>(x, xt);
    build_wqk<<<8192, blk, 0, stream>>>(Wq, Wk, bq, bk, Wqk, bqk);
    cast_f2b<<<4096, blk, 0, stream>>>(Wv, Wvb, 8192ll * 1024);

    const long M1 = 1048576, M2 = 2097152, M8 = 8388608;

    // qk_t: M=8192 (b,t), N=2048 (h*256+o), K=1024 — gemm256 QKLAY (512 blocks)
    gemm256<1, 1><<<dim3(16, 32, 1), blk, 0, stream>>>(
        xt, 1024, 0, 0, Wqk, 1024, 0, 0, qkt, 2048, 0, 0, 1024,
        bqk, 0, nullptr, nullptr, 0);

    for (int q = 0; q < 2; ++q) {
        const long b0 = (long)q * 4;
        const bf16* xtq = xt + b0 * M1;
        // v(zb,zh;c,s) = Wv[zh](c,ci) . xt(b0+zb;s,ci)^T + bv[zh,c]
        // gemm256: x = zh + 8*ntile (XCD pin), y = m-tile(4), z = zb(4)
        gemm256<0, 0><<<dim3(64, 4, 4), blk, 0, stream>>>(
            Wvb, 1024, 0, M1, xtq, 1024, M1, 0, vbuf, 1024, M8, M1, 1024,
            bv, 1024, nullptr, nullptr, 0);
        // fused E + softmax -> attb bf16 (1024 blocks)
        attn_fused<<<dim3(32, 32, 1), blk, 0, stream>>>(
            qkt + b0 * M2, attb);
        // heads_t(zb,zh;t,c) = gamma[zh]*(attn(t,s).v(c,s)^T) + xt(b0+zb;t,c)
        gemm256<3, 0><<<dim3(64, 4, 4), blk, 0, stream>>>(
            attb, 1024, M8, M1, vbuf, 1024, M8, M1,
            ot, 1024, M8, M1, 1024,
            nullptr, 0, gamma, xtq, 1024);
        // attb dead: cast FC weights into its region (re-done each pass)
        cast_f2b<<<512, blk, 0, stream>>>(W1, W1b, 128 * 1024);
        cast_f2b<<<64, blk, 0, stream>>>(W2, W2b, 128 * 128);
        // y1c = relu(ot . W1^T + b1): M=32768, N=128, K=1024
        gemm_nt<4, 64, 0><<<dim3(1, 256, 1), blk, 0, stream>>>(
            ot, 1024, 0, 0, W1b, 1024, 0, 0, y1c, 128, 0, 0, 1024,
            b1, 0, nullptr, nullptr, 0, nullptr);
        // out = relu(y1c . W2^T + b2) scattered + x (pass-local rows)
        gemm_nt<5, 128, 0><<<dim3(1, 256, 1), blk, 0, stream>>>(
            y1c, 128, 0, 0, W2b, 128, 0, 0, out + b0 * M1, 0, 0, 0, 128,
            b2, 0, nullptr, nullptr, 0, x + b0 * M1);
    }
}

// Round 10
// 623.471 us; speedup vs baseline: 1.1265x; 1.0229x over previous
//
#include <hip/hip_runtime.h>
#include <hip/hip_bf16.h>

typedef __hip_bfloat16 bf16;
typedef __attribute__((ext_vector_type(8))) __bf16 bf16x8;
typedef __attribute__((ext_vector_type(4))) float f32x4;

#define BM 128
#define BN 128

typedef const __attribute__((address_space(1))) void gvoid;
typedef __attribute__((address_space(3))) void lvoid;

// ---------------------------------------------------------------------------
// gemm8p: 256x256-tile 8-phase counted-vmcnt NT GEMM (guide m195-m201 family).
// 512 thr = 8 waves (2M x 4N); per-wave C = (2 qm x 64) x (2 qn x 32) = 128x64.
// BK=64, NIT = K/128 iterations of 2 K-tiles, 8 phases/iter.
// LDS 128 KB: A 4 half-slots [128x64] + B 4 half-slots [128x64] (slot = 8192 elem).
//   tile t (t0=2I even -> slots 0,1; t1 odd -> slots 2,3), half hf -> A slot 2*(t&1)+hf.
// Phase p: [ds_read subtile; stage 1 half-tile; barrier; lgkmcnt0+schedbar; setprio1;
//           16 MFMA (one C-quadrant x K=64); setprio0; (P4/P8: vmcnt(4|0)); barrier]
// Stagger (audited): P1:read A0,B0(t0) stage A1(t1)->A3 | P2:read B1(t0) stage B0(t1)->B2
//  | P3:read A1(t0) stage A0(t0+2)->A0 | P4: stage B1(t0+2)->B1, vmcnt
//  | P5:read A0,B0(t1) stage A1(t0+2)->A1 | P6:read B1(t1) stage B0(t0+2)->B0
//  | P7:read A1(t1) stage A0(t1+2)->A2 | P8: stage B1(t1+2)->B3, vmcnt
// WAR: each stage targets a slot whose last ds_read is >=1 barrier earlier.
// RAW: vmcnt(4) at P4 drains carryover+P1+P2 (covers P5 reads); at P8 drains
// P3..P6 (covers next-iter P1/P2/P3 reads); last iter uses vmcnt(0).
// Swizzle: chunk c of a half: row=c>>3, s=c&7, global jc=s^(row&7); read
// (row,jc0) at row*64+((jc0^(row&7))<<3) -> 2-way banks (free, verified R6-R8).
// MODE 0: acc+bias[zh*sBiasZ+m] (v-proj); 3: gamma*acc+xt (PV); 1: acc+bias[n] (qk).
// ---------------------------------------------------------------------------
#define G8_BAR()  __builtin_amdgcn_s_barrier()
#define G8_LGKM() do { asm volatile("s_waitcnt lgkmcnt(0)" ::: "memory"); \
                       __builtin_amdgcn_sched_barrier(0); } while (0)
#define G8_LDA(SLOT) do { \
    _Pragma("unroll") for (int mi_ = 0; mi_ < 4; ++mi_) \
    _Pragma("unroll") for (int ks_ = 0; ks_ < 2; ++ks_) \
        af[mi_][ks_] = *(const bf16x8*)(lds + (SLOT) * 8192 + offA[mi_][ks_]); } while (0)
#define G8_LDB(SLOT, BF) do { \
    _Pragma("unroll") for (int ni_ = 0; ni_ < 2; ++ni_) \
    _Pragma("unroll") for (int ks_ = 0; ks_ < 2; ++ks_) \
        BF[ni_][ks_] = *(const bf16x8*)(lds + 32768 + (SLOT) * 8192 + offB[ni_][ks_]); } while (0)
#define G8_STA(SLOT, HF, T) do { \
    __builtin_amdgcn_global_load_lds((gvoid*)(Ab + aoff0 + (HF) * halfA + (T) * 64), \
        (lvoid*)(lds + (SLOT) * 8192 + wave * 512), 16, 0, 0); \
    __builtin_amdgcn_global_load_lds((gvoid*)(Ab + aoff1 + (HF) * halfA + (T) * 64), \
        (lvoid*)(lds + (SLOT) * 8192 + 4096 + wave * 512), 16, 0, 0); } while (0)
#define G8_STB(SLOT, HF, T) do { \
    __builtin_amdgcn_global_load_lds((gvoid*)(Bb + boff0 + (HF) * halfB + (T) * 64), \
        (lvoid*)(lds + 32768 + (SLOT) * 8192 + wave * 512), 16, 0, 0); \
    __builtin_amdgcn_global_load_lds((gvoid*)(Bb + boff1 + (HF) * halfB + (T) * 64), \
        (lvoid*)(lds + 32768 + (SLOT) * 8192 + 4096 + wave * 512), 16, 0, 0); } while (0)
#define G8_MM(QM, QN, BF) do { \
    _Pragma("unroll") for (int ks_ = 0; ks_ < 2; ++ks_) \
    _Pragma("unroll") for (int mi_ = 0; mi_ < 4; ++mi_) \
    _Pragma("unroll") for (int ni_ = 0; ni_ < 2; ++ni_) \
        acc[QM][mi_][QN][ni_] = __builtin_amdgcn_mfma_f32_16x16x32_bf16( \
            af[mi_][ks_], BF[ni_][ks_], acc[QM][mi_][QN][ni_], 0, 0, 0); } while (0)
#define G8_VM(MORE) do { if (MORE) asm volatile("s_waitcnt vmcnt(4)" ::: "memory"); \
                         else      asm volatile("s_waitcnt vmcnt(0)" ::: "memory"); } while (0)

template<int MODE, int QKLAY>
__global__ __launch_bounds__(512, 2)
void gemm8p(const bf16* __restrict__ A, long lda, long sAb, long sAh,
            const bf16* __restrict__ B, long ldb, long sBb, long sBh,
            void* __restrict__ Cv, long ldc, long sCb, long sCh,
            int K,
            const float* __restrict__ bias, long sBiasZ,
            const float* __restrict__ gamma,
            const bf16* __restrict__ xt, long ldxt)
{
    __shared__ bf16 lds[65536];                  // 128 KiB
    const int mt = QKLAY ? (blockIdx.x >> 3) : ((blockIdx.x >> 3) >> 2);
    const int nt = QKLAY ? (blockIdx.x & 7) : ((blockIdx.x >> 3) & 3);
    const int zh = QKLAY ? 0 : (blockIdx.x & 7);
    const int zb = QKLAY ? 0 : blockIdx.z;
    const bf16* Ab = A + (long)zb * sAb + (long)zh * sAh + (long)mt * 256 * lda;
    const bf16* Bb = B + (long)zb * sBb + (long)zh * sBh + (long)nt * 256 * ldb;
    const int tid = threadIdx.x;
    const int wave = tid >> 6, lane = tid & 63;
    const int col16 = lane & 15, quad = lane >> 4;
    const int wave_m = wave >> 2, wave_n = wave & 3;
    const long halfA = 128 * lda, halfB = 128 * ldb;

    // per-thread staging source offsets (chunks c0=tid, c1=512+tid of a half-tile)
    long aoff0, aoff1, boff0, boff1;
    {
        int c0 = tid, c1 = 512 + tid;
        int r0 = c0 >> 3, r1 = c1 >> 3;
        aoff0 = (long)r0 * lda + (((c0 & 7) ^ (r0 & 7)) << 3);
        aoff1 = (long)r1 * lda + (((c1 & 7) ^ (r1 & 7)) << 3);
        boff0 = (long)r0 * ldb + (((c0 & 7) ^ (r0 & 7)) << 3);
        boff1 = (long)r1 * ldb + (((c1 & 7) ^ (r1 & 7)) << 3);
    }

    // K-invariant LDS read element-offsets within a half-slot
    int offA[4][2], offB[2][2];
    #pragma unroll
    for (int mi = 0; mi < 4; ++mi) {
        int r = wave_m * 64 + mi * 16 + col16;
        #pragma unroll
        for (int ks = 0; ks < 2; ++ks)
            offA[mi][ks] = r * 64 + ((((ks << 2) + quad) ^ (r & 7)) << 3);
    }
    #pragma unroll
    for (int ni = 0; ni < 2; ++ni) {
        int r = wave_n * 32 + ni * 16 + col16;
        #pragma unroll
        for (int ks = 0; ks < 2; ++ks)
            offB[ni][ks] = r * 64 + ((((ks << 2) + quad) ^ (r & 7)) << 3);
    }

    f32x4 acc[2][4][2][2] = {};
    bf16x8 af[4][2], bf0[2][2], bf1[2][2];

    // prologue: tile0 full + A0(1), B1(1)  (6 halves, 12 loads)
    G8_STA(0, 0, 0);                 // A0(0)
    G8_STB(0, 0, 0);                 // B0(0)
    G8_STB(1, 1, 0);                 // B1(0)
    G8_STA(1, 1, 0);                 // A1(0)
    G8_STA(2, 0, 1);                 // A0(1)
    G8_STB(3, 1, 1);                 // B1(1)
    asm volatile("s_waitcnt vmcnt(4)" ::: "memory");   // tile0 landed
    G8_BAR();

    const int NIT = K >> 7;
    for (int I = 0; I < NIT; ++I) {
        const int t1 = 2 * I + 1;
        const bool more = (I + 1 < NIT);
        // P1: q(A0,B0) of t0
        G8_LDA(0); G8_LDB(0, bf0);
        G8_STA(3, 1, t1);
        G8_BAR(); G8_LGKM();
        __builtin_amdgcn_s_setprio(1); G8_MM(0, 0, bf0); __builtin_amdgcn_s_setprio(0);
        G8_BAR();
        // P2: q(A0,B1)
        G8_LDB(1, bf1);
        G8_STB(2, 0, t1);
        G8_BAR(); G8_LGKM();
        __builtin_amdgcn_s_setprio(1); G8_MM(0, 1, bf1); __builtin_amdgcn_s_setprio(0);
        G8_BAR();
        // P3: q(A1,B1)
        G8_LDA(1);
        if (more) G8_STA(0, 0, t1 + 1);
        G8_BAR(); G8_LGKM();
        __builtin_amdgcn_s_setprio(1); G8_MM(1, 1, bf1); __builtin_amdgcn_s_setprio(0);
        G8_BAR();
        // P4: q(A1,B0); vmcnt
        if (more) G8_STB(1, 1, t1 + 1);
        G8_BAR();
        __builtin_amdgcn_s_setprio(1); G8_MM(1, 0, bf0); __builtin_amdgcn_s_setprio(0);
        G8_VM(more);
        G8_BAR();
        // P5: q(A0,B0) of t1
        G8_LDA(2); G8_LDB(2, bf0);
        if (more) G8_STA(1, 1, t1 + 1);
        G8_BAR(); G8_LGKM();
        __builtin_amdgcn_s_setprio(1); G8_MM(0, 0, bf0); __builtin_amdgcn_s_setprio(0);
        G8_BAR();
        // P6: q(A0,B1)
        G8_LDB(3, bf1);
        if (more) G8_STB(0, 0, t1 + 1);
        G8_BAR(); G8_LGKM();
        __builtin_amdgcn_s_setprio(1); G8_MM(0, 1, bf1); __builtin_amdgcn_s_setprio(0);
        G8_BAR();
        // P7: q(A1,B1)
        G8_LDA(3);
        if (more) G8_STA(2, 0, t1 + 2);
        G8_BAR(); G8_LGKM();
        __builtin_amdgcn_s_setprio(1); G8_MM(1, 1, bf1); __builtin_amdgcn_s_setprio(0);
        G8_BAR();
        // P8: q(A1,B0); vmcnt
        if (more) G8_STB(3, 1, t1 + 2);
        G8_BAR();
        __builtin_amdgcn_s_setprio(1); G8_MM(1, 0, bf0); __builtin_amdgcn_s_setprio(0);
        G8_VM(more);
        G8_BAR();
    }

    const long m0 = (long)mt * 256 + wave_m * 64;
    const long n0 = (long)nt * 256 + wave_n * 32;
    float g = 0.f;
    if (MODE == 3) g = gamma[zh];
    #pragma unroll
    for (int qm = 0; qm < 2; ++qm) {
        #pragma unroll
        for (int mi = 0; mi < 4; ++mi) {
            #pragma unroll
            for (int qn = 0; qn < 2; ++qn) {
                #pragma unroll
                for (int ni = 0; ni < 2; ++ni) {
                    long mb = m0 + qm * 128 + mi * 16 + quad * 4;
                    long n  = n0 + qn * 128 + ni * 16 + col16;
                    if constexpr (MODE == 0) {
                        bf16* cp = (bf16*)Cv + (long)zb * sCb + (long)zh * sCh + mb * ldc + n;
                        const float* bp = bias + zh * sBiasZ + mb;
                        #pragma unroll
                        for (int r = 0; r < 4; ++r) {
                            *cp = __float2bfloat16(acc[qm][mi][qn][ni][r] + bp[r]);
                            cp += ldc;
                        }
                    } else if constexpr (MODE == 1) {
                        float bn = bias[n];
                        bf16* cp = (bf16*)Cv + mb * ldc + n;
                        #pragma unroll
                        for (int r = 0; r < 4; ++r) {
                            *cp = __float2bfloat16(acc[qm][mi][qn][ni][r] + bn);
                            cp += ldc;
                        }
                    } else {
                        bf16* cp = (bf16*)Cv + (long)zb * sCb + (long)zh * sCh + mb * ldc + n;
                        const bf16* xp = xt + (long)zb * 1048576 + mb * ldxt + n;
                        #pragma unroll
                        for (int r = 0; r < 4; ++r) {
                            float xv = __bfloat162float(*xp);
                            *cp = __float2bfloat16(g * acc[qm][mi][qn][ni][r] + xv);
                            cp += ldc;
                            xp += ldxt;
                        }
                    }
                }
            }
        }
    }
}

// NT GEMM: C[m,n] = sum_k A[m,k] * B[n,k]   (both row-major, K contiguous)
// MODE 4: C bf16 = relu(acc + bias[n])                       (fc1)
// MODE 5: out f32 scatter + residual (m local row; Cv/xf pre-offset per pass)
template<int MODE, int TBK, int LAYOUT>
__global__ __launch_bounds__(256)
void gemm_nt(const bf16* __restrict__ A, long lda, long sAb, long sAh,
             const bf16* __restrict__ B, long ldb, long sBb, long sBh,
             void* __restrict__ Cv, long ldc, long sCb, long sCh,
             int K,
             const float* __restrict__ bias, long sBiasZ,
             const float* __restrict__ gamma,
             const bf16* __restrict__ xt, long ldxt,
             const float* __restrict__ xf)
{
    __shared__ bf16 As[BM * TBK];
    __shared__ bf16 Bs[BN * TBK];
    const int bxt = (LAYOUT == 2) ? (blockIdx.x >> 3) : blockIdx.x;    // n-tile
    const int zb  = (LAYOUT == 2) ? blockIdx.z : (blockIdx.z >> 3);
    const int zh  = (LAYOUT == 2) ? (blockIdx.x & 7) : (blockIdx.z & 7);
    const bf16* Ab = A + (long)zb * sAb + (long)zh * sAh + (long)blockIdx.y * BM * lda;
    const bf16* Bb = B + (long)zb * sBb + (long)zh * sBh + (long)bxt * BN * ldb;
    const int tid  = threadIdx.x;
    const int wave = tid >> 6, lane = tid & 63;
    const int col  = lane & 15, quad = lane >> 4;
    const int wm = (wave & 1) * 64, wn = (wave >> 1) * 64;
    constexpr int CPR = TBK / 8;            // 16B chunks per row
    constexpr int NSLOT = TBK / 16;         // staging slots per operand
    constexpr int NX = TBK / 32;            // kk iterations

    const bf16* aAddr[NSLOT];
    const bf16* bAddr[NSLOT];
    #pragma unroll
    for (int i = 0; i < NSLOT; ++i) {
        int cbase = i * 256 + wave * 64;     // wave-uniform chunk base
        int c = cbase + lane;                // chunk id
        int m = c / CPR;                     // tile row
        int j = c % CPR;                     // chunk slot in row
        int kch = ((j ^ (m & 7)) << 3);      // swizzled k offset (elements)
        aAddr[i] = Ab + (long)m * lda + kch;
        bAddr[i] = Bb + (long)m * ldb + kch;
    }

    int offA[NX][4], offB[NX][4];
    #pragma unroll
    for (int x = 0; x < NX; ++x) {
        int kq = x * 4 + quad;               // (kk>>3)+quad with kk = x*32
        #pragma unroll
        for (int mi = 0; mi < 4; ++mi) {
            int m = wm + mi * 16 + col;
            offA[x][mi] = m * TBK + ((kq ^ (m & 7)) << 3);
            int n = wn + mi * 16 + col;
            offB[x][mi] = n * TBK + ((kq ^ (n & 7)) << 3);
        }
    }

    f32x4 acc[4][4] = {};

    for (int k0 = 0; k0 < K; k0 += TBK) {
        __syncthreads();
        #pragma unroll
        for (int i = 0; i < NSLOT; ++i) {
            int cbase = i * 256 + wave * 64;
            __builtin_amdgcn_global_load_lds(
                (gvoid*)aAddr[i], (lvoid*)(As + cbase * 8), 16, 0, 0);
            __builtin_amdgcn_global_load_lds(
                (gvoid*)bAddr[i], (lvoid*)(Bs + cbase * 8), 16, 0, 0);
            aAddr[i] += TBK;
            bAddr[i] += TBK;
        }
        __syncthreads();
        #pragma unroll
        for (int x = 0; x < NX; ++x) {
            bf16x8 af[4], bfr[4];
            #pragma unroll
            for (int mi = 0; mi < 4; ++mi)
                af[mi] = *(const bf16x8*)(As + offA[x][mi]);
            #pragma unroll
            for (int ni = 0; ni < 4; ++ni)
                bfr[ni] = *(const bf16x8*)(Bs + offB[x][ni]);
            #pragma unroll
            for (int mi = 0; mi < 4; ++mi)
                #pragma unroll
                for (int ni = 0; ni < 4; ++ni)
                    acc[mi][ni] = __builtin_amdgcn_mfma_f32_16x16x32_bf16(
                        af[mi], bfr[ni], acc[mi][ni], 0, 0, 0);
        }
    }

    const long m0 = (long)blockIdx.y * BM + wm;
    const long n0 = (long)bxt * BN + wn;
    float g = 0.f;
    if (MODE == 3) g = gamma[zh];

    float bn[4];
    if constexpr (MODE == 1 || MODE == 4 || MODE == 5) {
        #pragma unroll
        for (int ni = 0; ni < 4; ++ni)
            bn[ni] = bias[n0 + ni * 16 + col];
    }

    #pragma unroll
    for (int mi = 0; mi < 4; ++mi) {
        #pragma unroll
        for (int ni = 0; ni < 4; ++ni) {
            long mb = m0 + mi * 16 + quad * 4;
            long n  = n0 + ni * 16 + col;
            if constexpr (MODE == 0) {
                bf16* cp = (bf16*)Cv + (long)zb * sCb + (long)zh * sCh + mb * ldc + n;
                const float* bp = bias + zh * sBiasZ + mb;
                #pragma unroll
                for (int r = 0; r < 4; ++r) {
                    float v = acc[mi][ni][r] + bp[r];
                    *cp = __float2bfloat16(v);
                    cp += ldc;
                }
            } else if constexpr (MODE == 1) {
                bf16* cp = (bf16*)Cv + mb * ldc + n;
                #pragma unroll
                for (int r = 0; r < 4; ++r) {
                    float v = acc[mi][ni][r] + bn[ni];
                    *cp = __float2bfloat16(v);
                    cp += ldc;
                }
            } else if constexpr (MODE == 3) {
                bf16* cp = (bf16*)Cv + (long)zb * sCb + (long)zh * sCh + mb * ldc + n;
                const bf16* xp = xt + (long)zb * 1048576 + mb * ldxt + n;
                #pragma unroll
                for (int r = 0; r < 4; ++r) {
                    float xv = __bfloat162float(*xp);
                    *cp = __float2bfloat16(g * acc[mi][ni][r] + xv);
                    cp += ldc;
                    xp += ldxt;
                }
            } else if constexpr (MODE == 4) {
                bf16* cp = (bf16*)Cv + mb * ldc + n;
                #pragma unroll
                for (int r = 0; r < 4; ++r) {
                    float v = acc[mi][ni][r] + bn[ni];
                    v = v > 0.f ? v : 0.f;
                    *cp = __float2bfloat16(v);
                    cp += ldc;
                }
            } else {  // MODE 5
                #pragma unroll
                for (int r = 0; r < 4; ++r) {
                    long m = mb + r;
                    float v = acc[mi][ni][r] + bn[ni];
                    v = v > 0.f ? v : 0.f;
                    long bb = m >> 13, h = (m >> 10) & 7, t = m & 1023;
                    long oi = bb * 1048576 + (n * 8 + h) * 1024 + t;
                    ((float*)Cv)[oi] = v + xf[oi];
                }
            }
        }
    }
}

// Fused energy + softmax. Grid: (slices, T/32). Block 256 (4 waves).
__global__ __launch_bounds__(256, 2)
void attn_fused(const bf16* __restrict__ qk, bf16* __restrict__ attn)
{
    constexpr int PAD = 1032;
    __shared__ __align__(16) char smraw[40960];
    __shared__ float red[2][4][32];
    bf16* Qs = (bf16*)smraw;                  // [32][128]
    bf16* Ks = (bf16*)(smraw + 8192);         // [128][128]
    bf16* Sbuf = (bf16*)smraw;                // [16][PAD]

    const int z = blockIdx.x;
    const int zb = z >> 3, zh = z & 7;
    const int t0 = blockIdx.y * 32;
    const int tid = threadIdx.x, w = tid >> 6, lane = tid & 63;
    const int col = lane & 15, quad = lane >> 4;

    const bf16* Qbase = qk + ((long)zb * 1024 + t0) * 2048 + zh * 256;
    const bf16* Kbase = qk + (long)zb * 1024 * 2048 + zh * 256 + 128;

    #pragma unroll
    for (int i = 0; i < 2; ++i) {
        int cbase = i * 256 + w * 64;
        int c = cbase + lane;
        int m = c >> 4, j = c & 15;
        __builtin_amdgcn_global_load_lds(
            (gvoid*)(Qbase + (long)m * 2048 + ((j ^ (m & 7)) << 3)),
            (lvoid*)(Qs + cbase * 8), 16, 0, 0);
    }
    __syncthreads();
    bf16x8 af[2][4];
    #pragma unroll
    for (int mi = 0; mi < 2; ++mi) {
        int m = mi * 16 + col;
        #pragma unroll
        for (int ki = 0; ki < 4; ++ki)
            af[mi][ki] = *(const bf16x8*)(Qs + m * 128 + ((((ki << 2) + quad) ^ (m & 7)) << 3));
    }

    f32x4 acc[2][16] = {};
    #pragma unroll
    for (int si = 0; si < 8; ++si) {
        __syncthreads();
        const bf16* Kb = Kbase + (long)si * 128 * 2048;
        #pragma unroll
        for (int i = 0; i < 8; ++i) {
            int cbase = i * 256 + w * 64;
            int c = cbase + lane;
            int m = c >> 4, j = c & 15;
            __builtin_amdgcn_global_load_lds(
                (gvoid*)(Kb + (long)m * 2048 + ((j ^ (m & 7)) << 3)),
                (lvoid*)(Ks + cbase * 8), 16, 0, 0);
        }
        __syncthreads();
        bf16x8 bfr[2][4];
        #pragma unroll
        for (int ni = 0; ni < 2; ++ni) {
            int n = w * 32 + ni * 16 + col;
            #pragma unroll
            for (int ki = 0; ki < 4; ++ki)
                bfr[ni][ki] = *(const bf16x8*)(Ks + n * 128 + ((((ki << 2) + quad) ^ (n & 7)) << 3));
        }
        #pragma unroll
        for (int ki = 0; ki < 4; ++ki)
            #pragma unroll
            for (int mi = 0; mi < 2; ++mi)
                #pragma unroll
                for (int ni = 0; ni < 2; ++ni)
                    acc[mi][si * 2 + ni] = __builtin_amdgcn_mfma_f32_16x16x32_bf16(
                        af[mi][ki], bfr[ni][ki], acc[mi][si * 2 + ni], 0, 0, 0);
    }

    float rmx[2][4], rinv[2][4];
    #pragma unroll
    for (int mi = 0; mi < 2; ++mi)
        #pragma unroll
        for (int r = 0; r < 4; ++r) {
            float mx = acc[mi][0][r];
            #pragma unroll
            for (int j = 1; j < 16; ++j) mx = fmaxf(mx, acc[mi][j][r]);
            #pragma unroll
            for (int off = 1; off < 16; off <<= 1) mx = fmaxf(mx, __shfl_xor(mx, off, 64));
            rmx[mi][r] = mx;
        }
    if (col == 0) {
        #pragma unroll
        for (int mi = 0; mi < 2; ++mi)
            #pragma unroll
            for (int r = 0; r < 4; ++r)
                red[0][w][mi * 16 + quad * 4 + r] = rmx[mi][r];
    }
    __syncthreads();
    #pragma unroll
    for (int mi = 0; mi < 2; ++mi)
        #pragma unroll
        for (int r = 0; r < 4; ++r) {
            int row = mi * 16 + quad * 4 + r;
            rmx[mi][r] = fmaxf(fmaxf(red[0][0][row], red[0][1][row]),
                               fmaxf(red[0][2][row], red[0][3][row]));
        }
    #pragma unroll
    for (int mi = 0; mi < 2; ++mi)
        #pragma unroll
        for (int r = 0; r < 4; ++r) {
            float s = 0.f;
            #pragma unroll
            for (int j = 0; j < 16; ++j) {
                acc[mi][j][r] = __expf(acc[mi][j][r] - rmx[mi][r]);
                s += acc[mi][j][r];
            }
            #pragma unroll
            for (int off = 1; off < 16; off <<= 1) s += __shfl_xor(s, off, 64);
            rinv[mi][r] = s;
        }
    if (col == 0) {
        #pragma unroll
        for (int mi = 0; mi < 2; ++mi)
            #pragma unroll
            for (int r = 0; r < 4; ++r)
                red[1][w][mi * 16 + quad * 4 + r] = rinv[mi][r];
    }
    __syncthreads();
    #pragma unroll
    for (int mi = 0; mi < 2; ++mi)
        #pragma unroll
        for (int r = 0; r < 4; ++r) {
            int row = mi * 16 + quad * 4 + r;
            float s4 = red[1][0][row] + red[1][1][row] + red[1][2][row] + red[1][3][row];
            rinv[mi][r] = 1.0f / s4;
        }

    bf16* dst = attn + ((long)(zb * 8 + zh)) * 1048576 + (long)t0 * 1024;
    #pragma unroll
    for (int mi = 0; mi < 2; ++mi) {
        __syncthreads();
        #pragma unroll
        for (int j = 0; j < 16; ++j) {
            int colb = (j >> 1) * 128 + w * 32 + (j & 1) * 16 + col;
            #pragma unroll
            for (int r = 0; r < 4; ++r) {
                int rowh = quad * 4 + r;
                Sbuf[rowh * PAD + colb] = __float2bfloat16(acc[mi][j][r] * rinv[mi][r]);
            }
        }
        __syncthreads();
        #pragma unroll
        for (int i = 0; i < 8; ++i) {
            int c = i * 256 + tid;             // 16 rows x 128 chunks
            int rowh = c >> 7, jj = c & 127;
            bf16x8 vv = *(const bf16x8*)(Sbuf + rowh * PAD + jj * 8);
            *(bf16x8*)(dst + (long)(mi * 16 + rowh) * 1024 + jj * 8) = vv;
        }
    }
}

// x (B,C,T) f32 -> xt (B,T,C) bf16, 32x32 LDS tiles
__global__ __launch_bounds__(256)
void transpose_cast_x(const float* __restrict__ x, bf16* __restrict__ xt)
{
    __shared__ float tile[32][33];
    int b = blockIdx.z;
    int c0 = blockIdx.y * 32, t0 = blockIdx.x * 32;
    int tx = threadIdx.x & 31, ty = threadIdx.x >> 5;  // ty 0..7
    const float* xb = x + (long)b * 1024 * 1024;
    #pragma unroll
    for (int i = 0; i < 4; ++i) {
        int c = ty + i * 8;
        tile[c][tx] = xb[(long)(c0 + c) * 1024 + t0 + tx];
    }
    __syncthreads();
    bf16* xtb = xt + (long)b * 1024 * 1024;
    #pragma unroll
    for (int i = 0; i < 4; ++i) {
        int t = ty + i * 8;
        xtb[(long)(t0 + t) * 1024 + c0 + tx] = __float2bfloat16(tile[tx][t]);
    }
}

__global__ __launch_bounds__(256)
void cast_f2b(const float* __restrict__ in, bf16* __restrict__ out, long n)
{
    long i = (long)blockIdx.x * 256 + threadIdx.x;
    long stride = (long)gridDim.x * 256;
    for (; i < n; i += stride) out[i] = __float2bfloat16(in[i]);
}

// Build stacked qk weight (2048 x 1024 bf16)
__global__ __launch_bounds__(256)
void build_wqk(const float* __restrict__ Wq, const float* __restrict__ Wk,
               const float* __restrict__ bq, const float* __restrict__ bk,
               bf16* __restrict__ Wqk, float* __restrict__ biasqk)
{
    long i = (long)blockIdx.x * 256 + threadIdx.x;   // 2048*1024 total
    long r = i >> 10, c = i & 1023;
    long h = r >> 8, rr = r & 255;
    float v = (rr < 128) ? Wq[(h * 128 + rr) * 1024 + c]
                         : Wk[(h * 128 + (rr - 128)) * 1024 + c];
    Wqk[i] = __float2bfloat16(v);
    if (c == 0)
        biasqk[r] = (rr < 128) ? bq[h * 128 + rr] : bk[h * 128 + rr - 128];
}

extern "C" void kernel_launch(void* const* d_in, const int* in_sizes, int n_in,
                              void* d_out, int out_size, void* d_ws, size_t ws_size,
                              hipStream_t stream)
{
    const float* x     = (const float*)d_in[0];
    const float* Wq    = (const float*)d_in[1];
    const float* bq    = (const float*)d_in[2];
    const float* Wk    = (const float*)d_in[3];
    const float* bk    = (const float*)d_in[4];
    const float* Wv    = (const float*)d_in[5];
    const float* bv    = (const float*)d_in[6];
    const float* gamma = (const float*)d_in[7];
    const float* W1    = (const float*)d_in[8];
    const float* b1    = (const float*)d_in[9];
    const float* W2    = (const float*)d_in[10];
    const float* b2    = (const float*)d_in[11];
    float* out = (float*)d_out;

    char* base = (char*)d_ws;
    const long MB = 1048576;
    bf16*  xt   = (bf16*)(base);
    bf16*  Wvb  = (bf16*)(base + 16 * MB);
    bf16*  vbuf = (bf16*)(base + 32 * MB);
    bf16*  Wqk  = (bf16*)(base + 32 * MB);          // dead after qk-proj
    float* bqk  = (float*)(base + 36 * MB);         // dead after qk-proj
    bf16*  attb = (bf16*)(base + 96 * MB);
    bf16*  W1b  = (bf16*)(base + 96 * MB);          // post-O overlay, re-cast per pass
    bf16*  W2b  = (bf16*)(base + 96 * MB + 524288);
    bf16*  y1c  = (bf16*)(base + 97 * MB);          // 8 MiB per pass
    bf16*  ot   = (bf16*)(base + 160 * MB);
    bf16*  qkt  = (bf16*)(base + 224 * MB);

    dim3 blk(256);
    transpose_cast_x<<<dim3(32, 32, 8), blk, 0, stream>>>(x, xt);
    build_wqk<<<8192, blk, 0, stream>>>(Wq, Wk, bq, bk, Wqk, bqk);
    cast_f2b<<<4096, blk, 0, stream>>>(Wv, Wvb, 8192ll * 1024);

    const long M1 = 1048576, M2 = 2097152, M8 = 8388608;

    // qk_t: M=8192 (b,t), N=2048 (h*256+o), K=1024 — 8-phase, 256 blocks
    gemm8p<1, 1><<<dim3(256, 1, 1), dim3(512), 0, stream>>>(
        xt, 1024, 0, 0, Wqk, 1024, 0, 0, qkt, 2048, 0, 0, 1024,
        bqk, 0, nullptr, nullptr, 0);

    for (int q = 0; q < 2; ++q) {
        const long b0 = (long)q * 4;
        const bf16* xtq = xt + b0 * M1;
        // v(zb,zh;c,s) = Wv[zh](c,ci) . xt(b0+zb;s,ci)^T + bv[zh,c]
        // x = zh + 8*(mt*4+nt) (XCD-pinned head), z = zb: 512 blocks, 1/CU
        gemm8p<0, 0><<<dim3(128, 1, 4), dim3(512), 0, stream>>>(
            Wvb, 1024, 0, M1, xtq, 1024, M1, 0, vbuf, 1024, M8, M1, 1024,
            bv, 1024, nullptr, nullptr, 0);
        // fused E + softmax -> attb bf16 (1024 blocks)
        attn_fused<<<dim3(32, 32, 1), blk, 0, stream>>>(
            qkt + b0 * M2, attb);
        // heads_t(zb,zh;t,c) = gamma[zh]*(attn(t,s).v(c,s)^T) + xt(b0+zb;t,c)
        gemm8p<3, 0><<<dim3(128, 1, 4), dim3(512), 0, stream>>>(
            attb, 1024, M8, M1, vbuf, 1024, M8, M1,
            ot, 1024, M8, M1, 1024,
            nullptr, 0, gamma, xtq, 1024);
        // attb dead: cast FC weights into its region (re-done each pass)
        cast_f2b<<<512, blk, 0, stream>>>(W1, W1b, 128 * 1024);
        cast_f2b<<<64, blk, 0, stream>>>(W2, W2b, 128 * 128);
        // y1c = relu(ot . W1^T + b1): M=32768, N=128, K=1024
        gemm_nt<4, 64, 0><<<dim3(1, 256, 1), blk, 0, stream>>>(
            ot, 1024, 0, 0, W1b, 1024, 0, 0, y1c, 128, 0, 0, 1024,
            b1, 0, nullptr, nullptr, 0, nullptr);
        // out = relu(y1c . W2^T + b2) scattered + x (pass-local rows)
        gemm_nt<5, 128, 0><<<dim3(1, 256, 1), blk, 0, stream>>>(
            y1c, 128, 0, 0, W2b, 128, 0, 0, out + b0 * M1, 0, 0, 0, 128,
            b2, 0, nullptr, nullptr, 0, x + b0 * M1);
    }
}